// Round 6
// baseline (631.721 us; speedup 1.0000x reference)
//
#include <hip/hip_runtime.h>
#include <hip/hip_fp16.h>

#define EPSN 1e-12f
#define NB   1024            // coarse dst buckets (dst >> 8)
#define RB   256             // rows per coarse bucket (N / NB)
#define CHK  16384           // edges per count/scatter workgroup (nwg = 256)
#define NWGMAX 256           // scanA: one block-count per thread
#define GU   16              // gathers in flight per wave in accumulate
#define WQS  16384.0f        // weight quantization scale (14 bits)

__device__ __forceinline__ float rdlane(float v, int k) {
    return __int_as_float(__builtin_amdgcn_readlane(__float_as_int(v), k));
}
__device__ __forceinline__ float preluf(float x, float a) {
    return x >= 0.0f ? x : a * x;
}

// ---------------- K1 v2: in_feat(fp16) = feat_z @ weight, row-per-lane -----
// Each lane owns one row: acc[64] in VGPRs, weight read via wave-uniform
// loads. in_feat stored as fp16 (halves gather-side L2-miss traffic).
__global__ __launch_bounds__(256) void k_transform2(
    const float* __restrict__ feat, const float* __restrict__ weight,
    const float* __restrict__ bias, const float* __restrict__ prelu_a,
    __half* __restrict__ in_feat, float* __restrict__ out_anchor,
    int N, int totalWaves)
{
    const int lane  = threadIdx.x & 63;
    const int wid   = (int)((blockIdx.x * (size_t)blockDim.x + threadIdx.x) >> 6);
    const int tiles = (N + 63) >> 6;

    for (int tile = wid; tile < tiles; tile += totalWaves) {
        const int row = tile * 64 + lane;
        if (row >= N) continue;

        float acc[64];
        #pragma unroll
        for (int j = 0; j < 64; ++j) acc[j] = 0.0f;

        const float4* fp = (const float4*)(feat + (size_t)row * 128);
        for (int kc = 0; kc < 32; ++kc) {              // k in chunks of 4
            const float4 f = fp[kc];
            const float fs[4] = {f.x, f.y, f.z, f.w};
            #pragma unroll
            for (int kk = 0; kk < 4; ++kk) {
                const float fv = fs[kk];
                const float* wr = weight + (kc * 4 + kk) * 64;  // uniform addr
                #pragma unroll
                for (int j = 0; j < 64; ++j)
                    acc[j] = fmaf(fv, wr[j], acc[j]);
            }
        }

        uint4* op4 = (uint4*)(in_feat + (size_t)row * 64);
        if ((row & 3) == 0) {
            const float a = prelu_a[0];
            float ss = 0.0f;
            #pragma unroll
            for (int j = 0; j < 64; ++j) {
                acc[j] = preluf(acc[j] + bias[j], a);
                ss = fmaf(acc[j], acc[j], ss);
            }
            const float inv = 1.0f / fmaxf(sqrtf(ss), EPSN);
            float4* ap4 = (float4*)(out_anchor + (size_t)(row >> 2) * 64);
            #pragma unroll
            for (int j4 = 0; j4 < 16; ++j4)
                ap4[j4] = make_float4(acc[4*j4]*inv, acc[4*j4+1]*inv,
                                      acc[4*j4+2]*inv, acc[4*j4+3]*inv);
            const uint4 z = make_uint4(0u, 0u, 0u, 0u);
            #pragma unroll
            for (int j4 = 0; j4 < 8; ++j4) op4[j4] = z;   // for fallback path
        } else {
            unsigned uw[32];
            #pragma unroll
            for (int j = 0; j < 32; ++j) {
                const unsigned lo = __half_as_ushort(__float2half_rn(acc[2*j]));
                const unsigned hi = __half_as_ushort(__float2half_rn(acc[2*j+1]));
                uw[j] = lo | (hi << 16);
            }
            #pragma unroll
            for (int j4 = 0; j4 < 8; ++j4)
                op4[j4] = make_uint4(uw[4*j4], uw[4*j4+1], uw[4*j4+2], uw[4*j4+3]);
        }
    }
}

// ---------------- S1: per-block bucket histograms (NO global atomics) ------
// drops zero-message edges (src % 4 == 0 -> in_feat row is zero)
__global__ __launch_bounds__(256) void s_count2(
    const int* __restrict__ esrc, const int* __restrict__ edst, int E,
    unsigned* __restrict__ C)
{
    __shared__ unsigned hist[NB];
    for (int i = threadIdx.x; i < NB; i += 256) hist[i] = 0;
    __syncthreads();
    const int base = blockIdx.x * CHK;
    for (int r = 0; r < 4; ++r) {
        int d[16];
        #pragma unroll
        for (int i = 0; i < 16; ++i) {
            const int idx = base + (r * 16 + i) * 256 + threadIdx.x;
            d[i] = -1;
            if (idx < E) {
                const int s = esrc[idx];
                if ((s & 3) != 0) d[i] = edst[idx];
            }
        }
        #pragma unroll
        for (int i = 0; i < 16; ++i)
            if (d[i] >= 0) atomicAdd(&hist[((unsigned)d[i]) >> 8], 1u);
    }
    __syncthreads();
    for (int i = threadIdx.x; i < NB; i += 256)
        C[(size_t)blockIdx.x * NB + i] = hist[i];
}

// ---------------- S2a: per-bucket exclusive scan over blocks, IN PLACE -----
// block i scans C[blk][i] over blk (1/thread); rewrites excl prefix; T[i]=sum
__global__ __launch_bounds__(256) void s_scanA(
    unsigned* __restrict__ C, unsigned* __restrict__ T, int nwg)
{
    __shared__ unsigned sc[256];
    const int i = blockIdx.x;
    const int t = threadIdx.x;
    const unsigned my = (t < nwg) ? C[(size_t)t * NB + i] : 0u;
    sc[t] = my;
    __syncthreads();
    for (int off = 1; off < 256; off <<= 1) {
        unsigned x = (t >= off) ? sc[t - off] : 0u;
        __syncthreads();
        sc[t] += x;
        __syncthreads();
    }
    if (t < nwg) C[(size_t)t * NB + i] = sc[t] - my;
    if (t == 255) T[i] = sc[255];
}

// ---------------- S2b: exclusive scan over NB bucket totals ----------------
__global__ __launch_bounds__(1024) void s_scanB(
    const unsigned* __restrict__ T, unsigned* __restrict__ basep,
    unsigned* __restrict__ rs, int N)
{
    __shared__ unsigned sc[NB];
    const int t = threadIdx.x;
    unsigned my = T[t];
    sc[t] = my;
    __syncthreads();
    for (int off = 1; off < NB; off <<= 1) {
        unsigned a = (t >= off) ? sc[t - off] : 0u;
        __syncthreads();
        sc[t] += a;
        __syncthreads();
    }
    basep[t] = sc[t] - my;
    if (t == NB - 1) { basep[NB] = sc[t]; rs[N] = sc[t]; }
}

// ---------------- S3: scatter into coarse-sorted records (LDS cursors only)
__global__ __launch_bounds__(256) void s_scatter3(
    const int* __restrict__ esrc, const int* __restrict__ edst,
    const float* __restrict__ ew, int E,
    const unsigned* __restrict__ basep, const unsigned* __restrict__ PT,
    uint2* __restrict__ recs)
{
    __shared__ unsigned cur[NB];
    const int blk = blockIdx.x;
    for (int i = threadIdx.x; i < NB; i += 256)
        cur[i] = basep[i] + PT[(size_t)blk * NB + i];
    __syncthreads();
    const int base = blk * CHK;
    for (int r = 0; r < 4; ++r) {
        int s[16], d[16]; float wv[16];
        #pragma unroll
        for (int i = 0; i < 16; ++i) {
            const int idx = base + (r * 16 + i) * 256 + threadIdx.x;
            const bool ok = (idx < E);
            s[i]  = ok ? esrc[idx] : 0;
            d[i]  = ok ? edst[idx] : 0;
            wv[i] = ok ? ew[idx]   : 0.0f;
            if (!ok || (s[i] & 3) == 0) d[i] = -1;   // pad or anchor-src: skip
        }
        #pragma unroll
        for (int i = 0; i < 16; ++i) {
            if (d[i] >= 0) {
                const unsigned slot = atomicAdd(&cur[((unsigned)d[i]) >> 8], 1u);
                const unsigned pack =
                    ((unsigned)s[i]) | ((((unsigned)d[i]) & 255u) << 18);
                recs[slot] = make_uint2(pack, __float_as_uint(wv[i]));
            }
        }
    }
}

// ---------------- S4: per-bucket fine sort -> 4B records -------------------
// output record: src (bits 0..17) | wq (bits 18..31), wq = round(w * 16384)
__global__ __launch_bounds__(256) void s_sortfine(
    const uint2* __restrict__ recs, const unsigned* __restrict__ basep,
    unsigned* __restrict__ recf, unsigned* __restrict__ rs)
{
    __shared__ unsigned hist[RB], sc[RB], cur[RB];
    const int t = threadIdx.x;
    const int b = blockIdx.x;
    const unsigned start = basep[b], end = basep[b + 1];
    hist[t] = 0;
    __syncthreads();
    for (unsigned i = start + t; i < end; i += 256)
        atomicAdd(&hist[recs[i].x >> 18], 1u);
    __syncthreads();
    sc[t] = hist[t];
    __syncthreads();
    for (int off = 1; off < RB; off <<= 1) {
        unsigned v = (t >= off) ? sc[t - off] : 0u;
        __syncthreads();
        sc[t] += v;
        __syncthreads();
    }
    const unsigned excl = sc[t] - hist[t];
    cur[t] = start + excl;
    rs[b * RB + t] = start + excl;
    __syncthreads();
    for (unsigned i = start + t; i < end; i += 256) {
        uint2 r = recs[i];
        unsigned slot = atomicAdd(&cur[r.x >> 18], 1u);
        unsigned wq = (unsigned)(__uint_as_float(r.y) * WQS + 0.5f);
        wq = min(wq, 16383u);
        recf[slot] = (r.x & 0x3FFFFu) | (wq << 18);
    }
}

// ---------------- S5: one wave per dst row, register accumulation ----------
// fp16 in_feat: half the gather bytes. 4B records: 1 readlane/edge;
// integer weights accumulated, scaled once per row.
__global__ __launch_bounds__(256) void s_accum4(
    const __half* __restrict__ in_feat, const unsigned* __restrict__ recf,
    const unsigned* __restrict__ rs, float* __restrict__ h,
    int NROWS, int totalWaves)
{
    const int lane = threadIdx.x & 63;
    const int wid = (int)((blockIdx.x * (size_t)blockDim.x + threadIdx.x) >> 6);

    for (int row = wid; row < NROWS; row += totalWaves) {
        const unsigned s = rs[row], e = rs[row + 1];
        float acc = 0.0f;
        unsigned done = s;
        while (done < e) {
            const int c = (int)min(64u, e - done);
            unsigned rcd = 0u;
            if (lane < c) rcd = recf[done + lane];   // coalesced 4B x c
            for (int j0 = 0; j0 < c; j0 += GU) {
                float v[GU], wj[GU];
                #pragma unroll
                for (int jj = 0; jj < GU; ++jj) {
                    const int idx = j0 + jj;
                    const int cl  = (idx < c) ? idx : (c - 1);
                    const unsigned px =
                        (unsigned)__builtin_amdgcn_readlane((int)rcd, cl);
                    v[jj]  = __half2float(
                        in_feat[((size_t)(px & 0x3FFFFu) << 6) + lane]);
                    wj[jj] = (idx < c) ? (float)(px >> 18) : 0.0f;
                }
                #pragma unroll
                for (int jj = 0; jj < GU; ++jj) acc = fmaf(v[jj], wj[jj], acc);
            }
            done += (unsigned)c;
        }
        h[((size_t)row << 6) + lane] = acc * (1.0f / WQS);
    }
}

// ---------------- fallback K2 (atomic scatter) ----------------------------
#define K2_U 8
__global__ __launch_bounds__(256) void k_edges(
    const __half* __restrict__ in_feat, const int* __restrict__ esrc,
    const int* __restrict__ edst, const float* __restrict__ ew,
    float* __restrict__ h, int E, int totalWaves)
{
    const int lane = threadIdx.x & 63;
    int wid = (int)((blockIdx.x * (size_t)blockDim.x + threadIdx.x) >> 6);
    wid = __builtin_amdgcn_readfirstlane(wid);
    const int chunk = (E + totalWaves - 1) / totalWaves;
    int e0 = wid * chunk;
    int e1 = min(e0 + chunk, E);
    for (int base = e0; base < e1; base += K2_U) {
        const int nb = min(K2_U, e1 - base);
        int s[K2_U], d[K2_U]; float w[K2_U];
        #pragma unroll
        for (int j = 0; j < K2_U; ++j) {
            int idx = base + ((j < nb) ? j : 0);
            s[j] = esrc[idx]; d[j] = edst[idx]; w[j] = ew[idx];
        }
        float v[K2_U];
        #pragma unroll
        for (int j = 0; j < K2_U; ++j)
            v[j] = __half2float(in_feat[((size_t)s[j] << 6) + lane]);
        #pragma unroll
        for (int j = 0; j < K2_U; ++j)
            if (j < nb) atomicAdd(h + ((size_t)d[j] << 6) + lane, v[j] * w[j]);
    }
}

// ---------------- K3: activation + pool + two GEMVs + l2norm --------------
__global__ __launch_bounds__(256) void k_finalize(
    const float* __restrict__ h, const float* __restrict__ bias,
    const float* __restrict__ prelu_a,
    const float* __restrict__ w_sub, const float* __restrict__ b_sub,
    const float* __restrict__ w_gcn, const float* __restrict__ b_gcn,
    float* __restrict__ out_sub, float* __restrict__ out_gcn,
    int G, int totalWaves)
{
    const int lane = threadIdx.x & 63;
    const int wid = (int)((blockIdx.x * (size_t)blockDim.x + threadIdx.x) >> 6);

    float wsreg[64], wgreg[64];
    #pragma unroll
    for (int k = 0; k < 64; ++k) wsreg[k] = w_sub[lane * 64 + k];
    #pragma unroll
    for (int k = 0; k < 64; ++k) wgreg[k] = w_gcn[lane * 64 + k];
    const float bj  = bias[lane];
    const float bsj = b_sub[lane];
    const float bgj = b_gcn[lane];
    const float a   = prelu_a[0];

    for (int g = wid; g < G; g += totalWaves) {
        const float* hp = h + (size_t)g * 256;
        float p0 = preluf(hp[lane]       + bj, a);
        float p1 = preluf(hp[64  + lane] + bj, a);
        float p2 = preluf(hp[128 + lane] + bj, a);
        float p3 = preluf(hp[192 + lane] + bj, a);
        float pool = (p0 + p1 + p2 + p3) * 0.25f;
        float gcn  = p0;

        float as = bsj, ag = bgj;
        #pragma unroll
        for (int k = 0; k < 64; ++k) {
            as = fmaf(rdlane(pool, k), wsreg[k], as);
            ag = fmaf(rdlane(gcn,  k), wgreg[k], ag);
        }
        float ss = as * as, sg = ag * ag;
        #pragma unroll
        for (int off = 32; off >= 1; off >>= 1) {
            ss += __shfl_xor(ss, off, 64);
            sg += __shfl_xor(sg, off, 64);
        }
        out_sub[(size_t)g * 64 + lane] = as / fmaxf(sqrtf(ss), EPSN);
        out_gcn[(size_t)g * 64 + lane] = ag / fmaxf(sqrtf(sg), EPSN);
    }
}

extern "C" void kernel_launch(void* const* d_in, const int* in_sizes, int n_in,
                              void* d_out, int out_size, void* d_ws, size_t ws_size,
                              hipStream_t stream)
{
    const float* feat    = (const float*)d_in[0];
    const int*   esrc    = (const int*)  d_in[1];
    const int*   edst    = (const int*)  d_in[2];
    const float* ew      = (const float*)d_in[3];
    const float* weight  = (const float*)d_in[4];
    const float* bias    = (const float*)d_in[5];
    const float* prelu_a = (const float*)d_in[6];
    const float* w_sub   = (const float*)d_in[7];
    const float* b_sub   = (const float*)d_in[8];
    const float* w_gcn   = (const float*)d_in[9];
    const float* b_gcn   = (const float*)d_in[10];

    const int N = in_sizes[0] / 128;
    const int E = in_sizes[1];
    const int G = N / 4;
    const int nwg = (E + CHK - 1) / CHK;

    // ws layout (sorted path; bytes). AH = N*64*2 (fp16), A = N*64*4:
    //   in_feat : [0, AH)
    //   h       : [AH, AH+A)     -- written by s_accum4 (after sortfine)
    //   recs    : [AH, AH+E*8)   -- overlays h; dead before s_accum4 runs
    //   recf    : [AH+A, +E*4)
    //   C       : nwg*NB*4          (scanned IN PLACE; doubles as PT)
    //   T       : NB*4
    //   basep   : (NB+1)*4
    //   rs      : (N+1)*4
    char* wsb = (char*)d_ws;
    const size_t AH    = (size_t)N * 64 * 2;
    const size_t A     = (size_t)N * 64 * 4;
    const size_t offRf = AH + A;
    const size_t offC  = offRf + (size_t)E * 4;
    const size_t offT  = offC  + (size_t)nwg * NB * 4;
    const size_t offBp = offT  + (size_t)NB * 4;
    const size_t offRs = offBp + (size_t)(NB + 1) * 4;
    const size_t ws_need = offRs + (size_t)(N + 1) * 4;

    __half*   in_feat = (__half*)wsb;
    float*    h       = (float*)(wsb + AH);
    uint2*    recs    = (uint2*)(wsb + AH);
    unsigned* recf    = (unsigned*)(wsb + offRf);
    unsigned* C       = (unsigned*)(wsb + offC);
    unsigned* T       = (unsigned*)(wsb + offT);
    unsigned* basep   = (unsigned*)(wsb + offBp);
    unsigned* rs      = (unsigned*)(wsb + offRs);

    float* out        = (float*)d_out;
    float* out_sub    = out;
    float* out_anchor = out + (size_t)G * 64;
    float* out_gcn    = out + (size_t)2 * G * 64;

    const bool sorted_path =
        (N == NB * RB) && (nwg <= NWGMAX) && ((size_t)E * 8 <= A) &&
        (ws_size >= ws_need);

    {   // K1: one tile (64 rows) per wave
        const int blocks = 1024, tw = blocks * 4;
        k_transform2<<<blocks, 256, 0, stream>>>(feat, weight, bias, prelu_a,
                                                 in_feat, out_anchor, N, tw);
    }

    if (sorted_path) {
        s_count2  <<<nwg, 256, 0, stream>>>(esrc, edst, E, C);
        s_scanA   <<<NB, 256, 0, stream>>>(C, T, nwg);
        s_scanB   <<<1, 1024, 0, stream>>>(T, basep, rs, N);
        s_scatter3<<<nwg, 256, 0, stream>>>(esrc, edst, ew, E, basep, C, recs);
        s_sortfine<<<NB, 256, 0, stream>>>(recs, basep, recf, rs);
        {
            const int blocks = 2048, tw = blocks * 4;   // 8192 waves, 32 rows each
            s_accum4<<<blocks, 256, 0, stream>>>(in_feat, recf, rs, h, N, tw);
        }
        {
            const int blocks = 4096, tw = blocks * 4;
            k_finalize<<<blocks, 256, 0, stream>>>(h, bias, prelu_a, w_sub, b_sub,
                                                   w_gcn, b_gcn, out_sub, out_gcn, G, tw);
        }
    } else if (ws_size >= AH + A) {
        hipMemsetAsync(h, 0, A, stream);
        const int blocks = 2048, tw = blocks * 4;
        k_edges<<<blocks, 256, 0, stream>>>(in_feat, esrc, edst, ew, h, E, tw);
        const int fblocks = 4096, ftw = fblocks * 4;
        k_finalize<<<fblocks, 256, 0, stream>>>(h, bias, prelu_a, w_sub, b_sub,
                                                w_gcn, b_gcn, out_sub, out_gcn, G, ftw);
    }
}

// Round 7
// 567.262 us; speedup vs baseline: 1.1136x; 1.1136x over previous
//
#include <hip/hip_runtime.h>
#include <hip/hip_fp16.h>

#define EPSN 1e-12f
#define NBC  256             // coarse dst buckets (dst >> 10), 1024 rows each
#define RBF  1024            // rows per coarse bucket
#define CHK  8192            // edges per count/scatter workgroup (nwg = 512)
#define NWGMAX 1024          // scanA handles up to 4 block-counts per thread
#define GU   16              // gathers in flight per wave in accumulate
#define WQS  16384.0f        // weight quantization scale (14 bits)

__device__ __forceinline__ float rdlane(float v, int k) {
    return __int_as_float(__builtin_amdgcn_readlane(__float_as_int(v), k));
}
__device__ __forceinline__ float preluf(float x, float a) {
    return x >= 0.0f ? x : a * x;
}
__device__ __forceinline__ unsigned pk16(float a, float b) {
    return (unsigned)__half_as_ushort(__float2half_rn(a)) |
           ((unsigned)__half_as_ushort(__float2half_rn(b)) << 16);
}

// ---------------- K1: in_feat(fp16) = feat_z @ weight, row-per-lane --------
// acc[64] in VGPRs; weight via wave-uniform loads. fp16 conversion is done in
// 8-element chunks stored immediately (NO wide temp array co-live with acc —
// R6's uw[32] caused a regalloc spill: VGPR_Count 56 < 64 needed).
__global__ __launch_bounds__(256) void k_transform2(
    const float* __restrict__ feat, const float* __restrict__ weight,
    const float* __restrict__ bias, const float* __restrict__ prelu_a,
    __half* __restrict__ in_feat, float* __restrict__ out_anchor,
    int N, int totalWaves)
{
    const int lane  = threadIdx.x & 63;
    const int wid   = (int)((blockIdx.x * (size_t)blockDim.x + threadIdx.x) >> 6);
    const int tiles = (N + 63) >> 6;

    for (int tile = wid; tile < tiles; tile += totalWaves) {
        const int row = tile * 64 + lane;
        if (row >= N) continue;

        float acc[64];
        #pragma unroll
        for (int j = 0; j < 64; ++j) acc[j] = 0.0f;

        const float4* fp = (const float4*)(feat + (size_t)row * 128);
        #pragma unroll 4
        for (int kc = 0; kc < 32; ++kc) {              // k in chunks of 4
            const float4 f = fp[kc];
            const float fs[4] = {f.x, f.y, f.z, f.w};
            #pragma unroll
            for (int kk = 0; kk < 4; ++kk) {
                const float fv = fs[kk];
                const float* wr = weight + (kc * 4 + kk) * 64;  // uniform addr
                #pragma unroll
                for (int j = 0; j < 64; ++j)
                    acc[j] = fmaf(fv, wr[j], acc[j]);
            }
        }

        uint4* op4 = (uint4*)(in_feat + (size_t)row * 64);
        if ((row & 3) == 0) {
            const float a = prelu_a[0];
            float ss = 0.0f;
            #pragma unroll
            for (int j = 0; j < 64; ++j) {
                acc[j] = preluf(acc[j] + bias[j], a);
                ss = fmaf(acc[j], acc[j], ss);
            }
            const float inv = 1.0f / fmaxf(sqrtf(ss), EPSN);
            float4* ap4 = (float4*)(out_anchor + (size_t)(row >> 2) * 64);
            #pragma unroll
            for (int j4 = 0; j4 < 16; ++j4)
                ap4[j4] = make_float4(acc[4*j4]*inv, acc[4*j4+1]*inv,
                                      acc[4*j4+2]*inv, acc[4*j4+3]*inv);
            const uint4 z = make_uint4(0u, 0u, 0u, 0u);
            #pragma unroll
            for (int j8 = 0; j8 < 8; ++j8) op4[j8] = z;   // for fallback path
        } else {
            #pragma unroll
            for (int j8 = 0; j8 < 8; ++j8) {
                uint4 u;
                u.x = pk16(acc[8*j8+0], acc[8*j8+1]);
                u.y = pk16(acc[8*j8+2], acc[8*j8+3]);
                u.z = pk16(acc[8*j8+4], acc[8*j8+5]);
                u.w = pk16(acc[8*j8+6], acc[8*j8+7]);
                op4[j8] = u;
            }
        }
    }
}

// ---------------- S1: per-block bucket histograms (NO global atomics) ------
// drops zero-message edges (src % 4 == 0 -> in_feat row is zero)
__global__ __launch_bounds__(256) void s_count2(
    const int* __restrict__ esrc, const int* __restrict__ edst, int E,
    unsigned* __restrict__ C)
{
    __shared__ unsigned hist[NBC];
    const int t = threadIdx.x;
    hist[t] = 0;
    __syncthreads();
    const int base = blockIdx.x * CHK;
    for (int r = 0; r < CHK / (16 * 256); ++r) {
        int d[16];
        #pragma unroll
        for (int i = 0; i < 16; ++i) {
            const int idx = base + (r * 16 + i) * 256 + t;
            d[i] = -1;
            if (idx < E) {
                const int s = esrc[idx];
                if ((s & 3) != 0) d[i] = edst[idx];
            }
        }
        #pragma unroll
        for (int i = 0; i < 16; ++i)
            if (d[i] >= 0) atomicAdd(&hist[((unsigned)d[i]) >> 10], 1u);
    }
    __syncthreads();
    C[(size_t)blockIdx.x * NBC + t] = hist[t];
}

// ---------------- S2a: per-bucket exclusive scan over blocks, IN PLACE -----
// block i scans C[blk][i] over blk; rewrites excl prefix; T[i] = bucket total
__global__ __launch_bounds__(256) void s_scanA(
    unsigned* __restrict__ C, unsigned* __restrict__ T, int nwg)
{
    __shared__ unsigned ssum[256];
    const int i = blockIdx.x;
    const int t = threadIdx.x;
    const int PER = (nwg + 255) / 256;           // <= 4
    unsigned vals[4];
    unsigned run = 0;
    for (int p = 0; p < PER; ++p) {
        const int blk = t * PER + p;
        const unsigned v = (blk < nwg) ? C[(size_t)blk * NBC + i] : 0u;
        vals[p] = run;
        run += v;
    }
    ssum[t] = run;
    __syncthreads();
    for (int off = 1; off < 256; off <<= 1) {
        unsigned x = (t >= off) ? ssum[t - off] : 0u;
        __syncthreads();
        ssum[t] += x;
        __syncthreads();
    }
    const unsigned texcl = ssum[t] - run;
    for (int p = 0; p < PER; ++p) {
        const int blk = t * PER + p;
        if (blk < nwg) C[(size_t)blk * NBC + i] = texcl + vals[p];
    }
    if (t == 255) T[i] = ssum[255];
}

// ---------------- S2b: exclusive scan over NBC bucket totals ---------------
__global__ __launch_bounds__(256) void s_scanB(
    const unsigned* __restrict__ T, unsigned* __restrict__ basep,
    unsigned* __restrict__ rs, int N)
{
    __shared__ unsigned sc[NBC];
    const int t = threadIdx.x;
    const unsigned my = T[t];
    sc[t] = my;
    __syncthreads();
    for (int off = 1; off < NBC; off <<= 1) {
        unsigned a = (t >= off) ? sc[t - off] : 0u;
        __syncthreads();
        sc[t] += a;
        __syncthreads();
    }
    basep[t] = sc[t] - my;
    if (t == NBC - 1) { basep[NBC] = sc[t]; rs[N] = sc[t]; }
}

// ---------------- S3: block-local counting sort + coalesced flush ----------
// Fixes scatter write amplification (R5's s_scatter3 wrote ~60 dirty lines
// per wave; inferred ~230us). Records are placed bucket-sorted into a 64KB
// LDS buffer, then flushed linearly: consecutive threads -> consecutive
// global addresses in ~192B runs. record: x = src(18) | wq(14), y = dst.
__global__ __launch_bounds__(256) void s_scatter4(
    const int* __restrict__ esrc, const int* __restrict__ edst,
    const float* __restrict__ ew, int E,
    const unsigned* __restrict__ basep, const unsigned* __restrict__ C,
    const unsigned* __restrict__ T, int nwg,
    uint2* __restrict__ recs)
{
    __shared__ uint2    buf[CHK];        // 64 KB
    __shared__ unsigned cur[NBC];        // local cursor (starts at local excl)
    __shared__ unsigned cb [NBC];        // global_base - local_excl
    __shared__ unsigned ssum[256];
    const int blk = blockIdx.x;
    const int t   = threadIdx.x;

    // this block's per-bucket count, derived from the scanned C matrix
    const unsigned own = C[(size_t)blk * NBC + t];
    const unsigned nxt = (blk + 1 < nwg) ? C[(size_t)(blk + 1) * NBC + t] : T[t];
    const unsigned myc = nxt - own;
    ssum[t] = myc;
    __syncthreads();
    for (int off = 1; off < 256; off <<= 1) {
        unsigned x = (t >= off) ? ssum[t - off] : 0u;
        __syncthreads();
        ssum[t] += x;
        __syncthreads();
    }
    const unsigned excl = ssum[t] - myc;
    cur[t] = excl;
    cb[t]  = basep[t] + own - excl;      // unsigned wrap ok: cb + i >= 0
    __syncthreads();
    const unsigned cnt = ssum[255];

    const int base = blk * CHK;
    for (int r = 0; r < CHK / (16 * 256); ++r) {
        int s[16], d[16]; float wv[16];
        #pragma unroll
        for (int i = 0; i < 16; ++i) {
            const int idx = base + (r * 16 + i) * 256 + t;
            const bool ok = (idx < E);
            s[i]  = ok ? esrc[idx] : 0;
            d[i]  = ok ? edst[idx] : 0;
            wv[i] = ok ? ew[idx]   : 0.0f;
            if (!ok || (s[i] & 3) == 0) d[i] = -1;   // pad or anchor-src: skip
        }
        #pragma unroll
        for (int i = 0; i < 16; ++i) {
            if (d[i] >= 0) {
                const unsigned slot = atomicAdd(&cur[((unsigned)d[i]) >> 10], 1u);
                const unsigned wq =
                    min((unsigned)(wv[i] * WQS + 0.5f), 16383u);
                buf[slot] = make_uint2(((unsigned)s[i]) | (wq << 18),
                                       (unsigned)d[i]);
            }
        }
    }
    __syncthreads();
    for (unsigned i = t; i < cnt; i += 256) {      // coalesced flush
        const uint2 rr = buf[i];
        recs[cb[rr.y >> 10] + i] = rr;
    }
}

// ---------------- S4: per-bucket fine sort (1024 rows) -> 4B records -------
// scattered writes stay within a 48KB region per block -> L2-absorbed.
__global__ __launch_bounds__(256) void s_sortfine(
    const uint2* __restrict__ recs, const unsigned* __restrict__ basep,
    unsigned* __restrict__ recf, unsigned* __restrict__ rs)
{
    __shared__ unsigned hist[RBF], cur[RBF], ssum[256];
    const int t = threadIdx.x;
    const int b = blockIdx.x;
    const unsigned start = basep[b], end = basep[b + 1];
    #pragma unroll
    for (int p = 0; p < 4; ++p) hist[t * 4 + p] = 0;
    __syncthreads();
    for (unsigned i = start + t; i < end; i += 256)
        atomicAdd(&hist[recs[i].y & (RBF - 1u)], 1u);
    __syncthreads();
    unsigned vals[4], run = 0;
    #pragma unroll
    for (int p = 0; p < 4; ++p) { vals[p] = run; run += hist[t * 4 + p]; }
    ssum[t] = run;
    __syncthreads();
    for (int off = 1; off < 256; off <<= 1) {
        unsigned x = (t >= off) ? ssum[t - off] : 0u;
        __syncthreads();
        ssum[t] += x;
        __syncthreads();
    }
    const unsigned texcl = ssum[t] - run;
    #pragma unroll
    for (int p = 0; p < 4; ++p) {
        const int i = t * 4 + p;
        const unsigned e = start + texcl + vals[p];
        cur[i] = e;
        rs[b * RBF + i] = e;
    }
    __syncthreads();
    for (unsigned i = start + t; i < end; i += 256) {
        const uint2 r = recs[i];
        const unsigned slot = atomicAdd(&cur[r.y & (RBF - 1u)], 1u);
        recf[slot] = r.x;
    }
}

// ---------------- S5: one wave per dst row, register accumulation ----------
// fp16 in_feat: half gather bytes. 4B records: 1 readlane/edge; integer
// weights accumulated, scaled once per row.
__global__ __launch_bounds__(256) void s_accum4(
    const __half* __restrict__ in_feat, const unsigned* __restrict__ recf,
    const unsigned* __restrict__ rs, float* __restrict__ h,
    int NROWS, int totalWaves)
{
    const int lane = threadIdx.x & 63;
    const int wid = (int)((blockIdx.x * (size_t)blockDim.x + threadIdx.x) >> 6);

    for (int row = wid; row < NROWS; row += totalWaves) {
        const unsigned s = rs[row], e = rs[row + 1];
        float acc = 0.0f;
        unsigned done = s;
        while (done < e) {
            const int c = (int)min(64u, e - done);
            unsigned rcd = 0u;
            if (lane < c) rcd = recf[done + lane];   // coalesced 4B x c
            for (int j0 = 0; j0 < c; j0 += GU) {
                float v[GU], wj[GU];
                #pragma unroll
                for (int jj = 0; jj < GU; ++jj) {
                    const int idx = j0 + jj;
                    const int cl  = (idx < c) ? idx : (c - 1);
                    const unsigned px =
                        (unsigned)__builtin_amdgcn_readlane((int)rcd, cl);
                    v[jj]  = __half2float(
                        in_feat[((size_t)(px & 0x3FFFFu) << 6) + lane]);
                    wj[jj] = (idx < c) ? (float)(px >> 18) : 0.0f;
                }
                #pragma unroll
                for (int jj = 0; jj < GU; ++jj) acc = fmaf(v[jj], wj[jj], acc);
            }
            done += (unsigned)c;
        }
        h[((size_t)row << 6) + lane] = acc * (1.0f / WQS);
    }
}

// ---------------- fallback K2 (atomic scatter) ----------------------------
#define K2_U 8
__global__ __launch_bounds__(256) void k_edges(
    const __half* __restrict__ in_feat, const int* __restrict__ esrc,
    const int* __restrict__ edst, const float* __restrict__ ew,
    float* __restrict__ h, int E, int totalWaves)
{
    const int lane = threadIdx.x & 63;
    int wid = (int)((blockIdx.x * (size_t)blockDim.x + threadIdx.x) >> 6);
    wid = __builtin_amdgcn_readfirstlane(wid);
    const int chunk = (E + totalWaves - 1) / totalWaves;
    int e0 = wid * chunk;
    int e1 = min(e0 + chunk, E);
    for (int base = e0; base < e1; base += K2_U) {
        const int nb = min(K2_U, e1 - base);
        int s[K2_U], d[K2_U]; float w[K2_U];
        #pragma unroll
        for (int j = 0; j < K2_U; ++j) {
            int idx = base + ((j < nb) ? j : 0);
            s[j] = esrc[idx]; d[j] = edst[idx]; w[j] = ew[idx];
        }
        float v[K2_U];
        #pragma unroll
        for (int j = 0; j < K2_U; ++j)
            v[j] = __half2float(in_feat[((size_t)s[j] << 6) + lane]);
        #pragma unroll
        for (int j = 0; j < K2_U; ++j)
            if (j < nb) atomicAdd(h + ((size_t)d[j] << 6) + lane, v[j] * w[j]);
    }
}

// ---------------- K3: activation + pool + two GEMVs + l2norm --------------
__global__ __launch_bounds__(256) void k_finalize(
    const float* __restrict__ h, const float* __restrict__ bias,
    const float* __restrict__ prelu_a,
    const float* __restrict__ w_sub, const float* __restrict__ b_sub,
    const float* __restrict__ w_gcn, const float* __restrict__ b_gcn,
    float* __restrict__ out_sub, float* __restrict__ out_gcn,
    int G, int totalWaves)
{
    const int lane = threadIdx.x & 63;
    const int wid = (int)((blockIdx.x * (size_t)blockDim.x + threadIdx.x) >> 6);

    float wsreg[64], wgreg[64];
    #pragma unroll
    for (int k = 0; k < 64; ++k) wsreg[k] = w_sub[lane * 64 + k];
    #pragma unroll
    for (int k = 0; k < 64; ++k) wgreg[k] = w_gcn[lane * 64 + k];
    const float bj  = bias[lane];
    const float bsj = b_sub[lane];
    const float bgj = b_gcn[lane];
    const float a   = prelu_a[0];

    for (int g = wid; g < G; g += totalWaves) {
        const float* hp = h + (size_t)g * 256;
        float p0 = preluf(hp[lane]       + bj, a);
        float p1 = preluf(hp[64  + lane] + bj, a);
        float p2 = preluf(hp[128 + lane] + bj, a);
        float p3 = preluf(hp[192 + lane] + bj, a);
        float pool = (p0 + p1 + p2 + p3) * 0.25f;
        float gcn  = p0;

        float as = bsj, ag = bgj;
        #pragma unroll
        for (int k = 0; k < 64; ++k) {
            as = fmaf(rdlane(pool, k), wsreg[k], as);
            ag = fmaf(rdlane(gcn,  k), wgreg[k], ag);
        }
        float ss = as * as, sg = ag * ag;
        #pragma unroll
        for (int off = 32; off >= 1; off >>= 1) {
            ss += __shfl_xor(ss, off, 64);
            sg += __shfl_xor(sg, off, 64);
        }
        out_sub[(size_t)g * 64 + lane] = as / fmaxf(sqrtf(ss), EPSN);
        out_gcn[(size_t)g * 64 + lane] = ag / fmaxf(sqrtf(sg), EPSN);
    }
}

extern "C" void kernel_launch(void* const* d_in, const int* in_sizes, int n_in,
                              void* d_out, int out_size, void* d_ws, size_t ws_size,
                              hipStream_t stream)
{
    const float* feat    = (const float*)d_in[0];
    const int*   esrc    = (const int*)  d_in[1];
    const int*   edst    = (const int*)  d_in[2];
    const float* ew      = (const float*)d_in[3];
    const float* weight  = (const float*)d_in[4];
    const float* bias    = (const float*)d_in[5];
    const float* prelu_a = (const float*)d_in[6];
    const float* w_sub   = (const float*)d_in[7];
    const float* b_sub   = (const float*)d_in[8];
    const float* w_gcn   = (const float*)d_in[9];
    const float* b_gcn   = (const float*)d_in[10];

    const int N = in_sizes[0] / 128;
    const int E = in_sizes[1];
    const int G = N / 4;
    const int nwg = (E + CHK - 1) / CHK;

    // ws layout (sorted path; bytes). AH = N*64*2 (fp16), A = N*64*4:
    //   in_feat : [0, AH)
    //   h       : [AH, AH+A)     -- written by s_accum4 (after sortfine)
    //   recs    : [AH, AH+E*8)   -- overlays h; dead before s_accum4 runs
    //   recf    : [AH+A, +E*4)
    //   C       : nwg*NBC*4         (scanned IN PLACE)
    //   T       : NBC*4
    //   basep   : (NBC+1)*4
    //   rs      : (N+1)*4
    char* wsb = (char*)d_ws;
    const size_t AH    = (size_t)N * 64 * 2;
    const size_t A     = (size_t)N * 64 * 4;
    const size_t offRf = AH + A;
    const size_t offC  = offRf + (size_t)E * 4;
    const size_t offT  = offC  + (size_t)nwg * NBC * 4;
    const size_t offBp = offT  + (size_t)NBC * 4;
    const size_t offRs = offBp + (size_t)(NBC + 1) * 4;
    const size_t ws_need = offRs + (size_t)(N + 1) * 4;

    __half*   in_feat = (__half*)wsb;
    float*    h       = (float*)(wsb + AH);
    uint2*    recs    = (uint2*)(wsb + AH);
    unsigned* recf    = (unsigned*)(wsb + offRf);
    unsigned* C       = (unsigned*)(wsb + offC);
    unsigned* T       = (unsigned*)(wsb + offT);
    unsigned* basep   = (unsigned*)(wsb + offBp);
    unsigned* rs      = (unsigned*)(wsb + offRs);

    float* out        = (float*)d_out;
    float* out_sub    = out;
    float* out_anchor = out + (size_t)G * 64;
    float* out_gcn    = out + (size_t)2 * G * 64;

    const bool sorted_path =
        (N == NBC * RBF) && (nwg <= NWGMAX) && ((size_t)E * 8 <= A) &&
        (ws_size >= ws_need);

    {   // K1: one 64-row tile per wave
        const int blocks = 1024, tw = blocks * 4;
        k_transform2<<<blocks, 256, 0, stream>>>(feat, weight, bias, prelu_a,
                                                 in_feat, out_anchor, N, tw);
    }

    if (sorted_path) {
        s_count2  <<<nwg, 256, 0, stream>>>(esrc, edst, E, C);
        s_scanA   <<<NBC, 256, 0, stream>>>(C, T, nwg);
        s_scanB   <<<1, 256, 0, stream>>>(T, basep, rs, N);
        s_scatter4<<<nwg, 256, 0, stream>>>(esrc, edst, ew, E, basep, C, T,
                                            nwg, recs);
        s_sortfine<<<NBC, 256, 0, stream>>>(recs, basep, recf, rs);
        {
            const int blocks = 2048, tw = blocks * 4;   // 8192 waves, 32 rows each
            s_accum4<<<blocks, 256, 0, stream>>>(in_feat, recf, rs, h, N, tw);
        }
        {
            const int blocks = 4096, tw = blocks * 4;
            k_finalize<<<blocks, 256, 0, stream>>>(h, bias, prelu_a, w_sub, b_sub,
                                                   w_gcn, b_gcn, out_sub, out_gcn, G, tw);
        }
    } else if (ws_size >= AH + A) {
        hipMemsetAsync(h, 0, A, stream);
        const int blocks = 2048, tw = blocks * 4;
        k_edges<<<blocks, 256, 0, stream>>>(in_feat, esrc, edst, ew, h, E, tw);
        const int fblocks = 4096, ftw = fblocks * 4;
        k_finalize<<<fblocks, 256, 0, stream>>>(h, bias, prelu_a, w_sub, b_sub,
                                                w_gcn, b_gcn, out_sub, out_gcn, G, ftw);
    }
}

// Round 8
// 518.701 us; speedup vs baseline: 1.2179x; 1.0936x over previous
//
#include <hip/hip_runtime.h>
#include <hip/hip_fp16.h>

#define EPSN 1e-12f
#define NBC  256             // coarse dst buckets (dst >> 10), 1024 rows each
#define RBF  1024            // rows per coarse bucket
#define CHK  8192            // edges per count/scatter workgroup (nwg = 512)
#define NWGMAX 1024          // scanA handles up to 4 block-counts per thread
#define GU   16              // gathers in flight per wave in accumulate
#define WQS  16384.0f        // weight quantization scale (14 bits)

typedef _Float16 half8_t __attribute__((ext_vector_type(8)));
typedef float    f32x4  __attribute__((ext_vector_type(4)));

__device__ __forceinline__ float rdlane(float v, int k) {
    return __int_as_float(__builtin_amdgcn_readlane(__float_as_int(v), k));
}
__device__ __forceinline__ float preluf(float x, float a) {
    return x >= 0.0f ? x : a * x;
}

// ---------------- K1 (MFMA): in_feat(fp16) = feat_z @ weight ---------------
// fp32 VALU floor for this GEMV-batch is ~27us (4.3 GFLOP / 157 TF) and R7
// measured 120us at 28% VALUBusy (s_load stalls). MFMA makes it memory-bound
// (~190 MB). Wave owns 16 rows x 64 cols: 4 C-tiles, K=128 in 4 steps.
// B-frags (whole weight, fp16) hoisted to 64 VGPRs per wave; no LDS.
// K-axis layout note: A and B frags use the SAME (lane,e)->k mapping, so any
// permutation cancels in the dot product; only row/col = lane&15 and the
// verified C layout (col=lane&15, row=(lane>>4)*4+reg) matter.
__global__ __launch_bounds__(256) void k_mfma(
    const float* __restrict__ feat, const float* __restrict__ weight,
    const float* __restrict__ bias, const float* __restrict__ prelu_a,
    __half* __restrict__ in_feat, float* __restrict__ out_anchor,
    int N, int totalWaves)
{
    const int lane = threadIdx.x & 63;
    const int r    = lane & 15;
    const int g    = lane >> 4;
    const int wid  = (int)((blockIdx.x * (size_t)blockDim.x + threadIdx.x) >> 6);
    const int nt4  = N >> 4;

    // hoist B-frags: col n = nt*16+r, k = kq*32 + g*8 + e (L2-hot scalar loads)
    half8_t bfr[4][4];
    #pragma unroll
    for (int nt = 0; nt < 4; ++nt)
        #pragma unroll
        for (int kq = 0; kq < 4; ++kq)
            #pragma unroll
            for (int e = 0; e < 8; ++e)
                bfr[nt][kq][e] =
                    (_Float16)weight[(kq * 32 + g * 8 + e) * 64 + nt * 16 + r];

    float bj[4];
    #pragma unroll
    for (int nt = 0; nt < 4; ++nt) bj[nt] = bias[nt * 16 + r];
    const float a = prelu_a[0];

    for (int t = wid; t < nt4; t += totalWaves) {
        const int rb = t << 4;

        f32x4 acc[4];
        #pragma unroll
        for (int nt = 0; nt < 4; ++nt) acc[nt] = (f32x4){0.f, 0.f, 0.f, 0.f};

        const float* fr = feat + (size_t)(rb + r) * 128 + g * 8;
        #pragma unroll
        for (int kq = 0; kq < 4; ++kq) {
            const float4 f0 = *(const float4*)(fr + kq * 32);
            const float4 f1 = *(const float4*)(fr + kq * 32 + 4);
            half8_t af;
            af[0] = (_Float16)f0.x; af[1] = (_Float16)f0.y;
            af[2] = (_Float16)f0.z; af[3] = (_Float16)f0.w;
            af[4] = (_Float16)f1.x; af[5] = (_Float16)f1.y;
            af[6] = (_Float16)f1.z; af[7] = (_Float16)f1.w;
            #pragma unroll
            for (int nt = 0; nt < 4; ++nt)
                acc[nt] = __builtin_amdgcn_mfma_f32_16x16x32_f16(
                    af, bfr[nt][kq], acc[nt], 0, 0, 0);
        }

        // C layout: col = nt*16 + r, row = rb + g*4 + reg. rb%16==0 =>
        // row%4 == reg => reg 0 rows are the anchors.
        const int row0 = rb + g * 4;
        float ss = 0.0f, y[4];
        #pragma unroll
        for (int nt = 0; nt < 4; ++nt) {
            y[nt] = preluf(acc[nt][0] + bj[nt], a);
            ss = fmaf(y[nt], y[nt], ss);
        }
        ss += __shfl_xor(ss, 1, 16);
        ss += __shfl_xor(ss, 2, 16);
        ss += __shfl_xor(ss, 4, 16);
        ss += __shfl_xor(ss, 8, 16);
        const float inv = 1.0f / fmaxf(sqrtf(ss), EPSN);
        #pragma unroll
        for (int nt = 0; nt < 4; ++nt)
            out_anchor[(size_t)(row0 >> 2) * 64 + nt * 16 + r] = y[nt] * inv;
        #pragma unroll
        for (int nt = 0; nt < 4; ++nt)
            in_feat[(size_t)row0 * 64 + nt * 16 + r] = __float2half(0.0f);
        #pragma unroll
        for (int reg = 1; reg < 4; ++reg)
            #pragma unroll
            for (int nt = 0; nt < 4; ++nt)
                in_feat[(size_t)(row0 + reg) * 64 + nt * 16 + r] =
                    __float2half(acc[nt][reg]);
    }
}

// ---------------- K1 fallback (VALU, row-per-lane) -------------------------
__global__ __launch_bounds__(256) void k_transform2(
    const float* __restrict__ feat, const float* __restrict__ weight,
    const float* __restrict__ bias, const float* __restrict__ prelu_a,
    __half* __restrict__ in_feat, float* __restrict__ out_anchor,
    int N, int totalWaves)
{
    const int lane  = threadIdx.x & 63;
    const int wid   = (int)((blockIdx.x * (size_t)blockDim.x + threadIdx.x) >> 6);
    const int tiles = (N + 63) >> 6;

    for (int tile = wid; tile < tiles; tile += totalWaves) {
        const int row = tile * 64 + lane;
        if (row >= N) continue;

        float acc[64];
        #pragma unroll
        for (int j = 0; j < 64; ++j) acc[j] = 0.0f;

        const float4* fp = (const float4*)(feat + (size_t)row * 128);
        #pragma unroll 4
        for (int kc = 0; kc < 32; ++kc) {
            const float4 f = fp[kc];
            const float fs[4] = {f.x, f.y, f.z, f.w};
            #pragma unroll
            for (int kk = 0; kk < 4; ++kk) {
                const float fv = fs[kk];
                const float* wr = weight + (kc * 4 + kk) * 64;
                #pragma unroll
                for (int j = 0; j < 64; ++j)
                    acc[j] = fmaf(fv, wr[j], acc[j]);
            }
        }

        if ((row & 3) == 0) {
            const float a = prelu_a[0];
            float ss = 0.0f;
            #pragma unroll
            for (int j = 0; j < 64; ++j) {
                acc[j] = preluf(acc[j] + bias[j], a);
                ss = fmaf(acc[j], acc[j], ss);
            }
            const float inv = 1.0f / fmaxf(sqrtf(ss), EPSN);
            float* ap = out_anchor + (size_t)(row >> 2) * 64;
            #pragma unroll
            for (int j = 0; j < 64; ++j) ap[j] = acc[j] * inv;
            #pragma unroll
            for (int j = 0; j < 64; ++j)
                in_feat[(size_t)row * 64 + j] = __float2half(0.0f);
        } else {
            #pragma unroll
            for (int j = 0; j < 64; ++j)
                in_feat[(size_t)row * 64 + j] = __float2half(acc[j]);
        }
    }
}

// ---------------- S1: per-block bucket histograms (NO global atomics) ------
// drops zero-message edges (src % 4 == 0 -> in_feat row is zero)
__global__ __launch_bounds__(256) void s_count2(
    const int* __restrict__ esrc, const int* __restrict__ edst, int E,
    unsigned* __restrict__ C)
{
    __shared__ unsigned hist[NBC];
    const int t = threadIdx.x;
    hist[t] = 0;
    __syncthreads();
    const int base = blockIdx.x * CHK;
    for (int r = 0; r < CHK / (16 * 256); ++r) {
        int d[16];
        #pragma unroll
        for (int i = 0; i < 16; ++i) {
            const int idx = base + (r * 16 + i) * 256 + t;
            d[i] = -1;
            if (idx < E) {
                const int s = esrc[idx];
                if ((s & 3) != 0) d[i] = edst[idx];
            }
        }
        #pragma unroll
        for (int i = 0; i < 16; ++i)
            if (d[i] >= 0) atomicAdd(&hist[((unsigned)d[i]) >> 10], 1u);
    }
    __syncthreads();
    C[(size_t)blockIdx.x * NBC + t] = hist[t];
}

// ---------------- S2a: per-bucket exclusive scan over blocks, IN PLACE -----
__global__ __launch_bounds__(256) void s_scanA(
    unsigned* __restrict__ C, unsigned* __restrict__ T, int nwg)
{
    __shared__ unsigned ssum[256];
    const int i = blockIdx.x;
    const int t = threadIdx.x;
    const int PER = (nwg + 255) / 256;           // <= 4
    unsigned vals[4];
    unsigned run = 0;
    for (int p = 0; p < PER; ++p) {
        const int blk = t * PER + p;
        const unsigned v = (blk < nwg) ? C[(size_t)blk * NBC + i] : 0u;
        vals[p] = run;
        run += v;
    }
    ssum[t] = run;
    __syncthreads();
    for (int off = 1; off < 256; off <<= 1) {
        unsigned x = (t >= off) ? ssum[t - off] : 0u;
        __syncthreads();
        ssum[t] += x;
        __syncthreads();
    }
    const unsigned texcl = ssum[t] - run;
    for (int p = 0; p < PER; ++p) {
        const int blk = t * PER + p;
        if (blk < nwg) C[(size_t)blk * NBC + i] = texcl + vals[p];
    }
    if (t == 255) T[i] = ssum[255];
}

// ---------------- S2b: exclusive scan over NBC bucket totals ---------------
__global__ __launch_bounds__(256) void s_scanB(
    const unsigned* __restrict__ T, unsigned* __restrict__ basep,
    unsigned* __restrict__ rs, int N)
{
    __shared__ unsigned sc[NBC];
    const int t = threadIdx.x;
    const unsigned my = T[t];
    sc[t] = my;
    __syncthreads();
    for (int off = 1; off < NBC; off <<= 1) {
        unsigned a = (t >= off) ? sc[t - off] : 0u;
        __syncthreads();
        sc[t] += a;
        __syncthreads();
    }
    basep[t] = sc[t] - my;
    if (t == NBC - 1) { basep[NBC] = sc[t]; rs[N] = sc[t]; }
}

// ---------------- S3: block-local counting sort + coalesced flush ----------
// record: x = src(18) | wq(14), y = dst.
__global__ __launch_bounds__(256) void s_scatter4(
    const int* __restrict__ esrc, const int* __restrict__ edst,
    const float* __restrict__ ew, int E,
    const unsigned* __restrict__ basep, const unsigned* __restrict__ C,
    const unsigned* __restrict__ T, int nwg,
    uint2* __restrict__ recs)
{
    __shared__ uint2    buf[CHK];        // 64 KB
    __shared__ unsigned cur[NBC];
    __shared__ unsigned cb [NBC];
    __shared__ unsigned ssum[256];
    const int blk = blockIdx.x;
    const int t   = threadIdx.x;

    const unsigned own = C[(size_t)blk * NBC + t];
    const unsigned nxt = (blk + 1 < nwg) ? C[(size_t)(blk + 1) * NBC + t] : T[t];
    const unsigned myc = nxt - own;
    ssum[t] = myc;
    __syncthreads();
    for (int off = 1; off < 256; off <<= 1) {
        unsigned x = (t >= off) ? ssum[t - off] : 0u;
        __syncthreads();
        ssum[t] += x;
        __syncthreads();
    }
    const unsigned excl = ssum[t] - myc;
    cur[t] = excl;
    cb[t]  = basep[t] + own - excl;
    __syncthreads();
    const unsigned cnt = ssum[255];

    const int base = blk * CHK;
    for (int r = 0; r < CHK / (16 * 256); ++r) {
        int s[16], d[16]; float wv[16];
        #pragma unroll
        for (int i = 0; i < 16; ++i) {
            const int idx = base + (r * 16 + i) * 256 + t;
            const bool ok = (idx < E);
            s[i]  = ok ? esrc[idx] : 0;
            d[i]  = ok ? edst[idx] : 0;
            wv[i] = ok ? ew[idx]   : 0.0f;
            if (!ok || (s[i] & 3) == 0) d[i] = -1;
        }
        #pragma unroll
        for (int i = 0; i < 16; ++i) {
            if (d[i] >= 0) {
                const unsigned slot = atomicAdd(&cur[((unsigned)d[i]) >> 10], 1u);
                const unsigned wq =
                    min((unsigned)(wv[i] * WQS + 0.5f), 16383u);
                buf[slot] = make_uint2(((unsigned)s[i]) | (wq << 18),
                                       (unsigned)d[i]);
            }
        }
    }
    __syncthreads();
    for (unsigned i = t; i < cnt; i += 256) {      // coalesced flush
        const uint2 rr = buf[i];
        recs[cb[rr.y >> 10] + i] = rr;
    }
}

// ---------------- S4: per-bucket fine sort (1024 rows) -> 4B records -------
__global__ __launch_bounds__(256) void s_sortfine(
    const uint2* __restrict__ recs, const unsigned* __restrict__ basep,
    unsigned* __restrict__ recf, unsigned* __restrict__ rs)
{
    __shared__ unsigned hist[RBF], cur[RBF], ssum[256];
    const int t = threadIdx.x;
    const int b = blockIdx.x;
    const unsigned start = basep[b], end = basep[b + 1];
    #pragma unroll
    for (int p = 0; p < 4; ++p) hist[t * 4 + p] = 0;
    __syncthreads();
    for (unsigned i = start + t; i < end; i += 256)
        atomicAdd(&hist[recs[i].y & (RBF - 1u)], 1u);
    __syncthreads();
    unsigned vals[4], run = 0;
    #pragma unroll
    for (int p = 0; p < 4; ++p) { vals[p] = run; run += hist[t * 4 + p]; }
    ssum[t] = run;
    __syncthreads();
    for (int off = 1; off < 256; off <<= 1) {
        unsigned x = (t >= off) ? ssum[t - off] : 0u;
        __syncthreads();
        ssum[t] += x;
        __syncthreads();
    }
    const unsigned texcl = ssum[t] - run;
    #pragma unroll
    for (int p = 0; p < 4; ++p) {
        const int i = t * 4 + p;
        const unsigned e = start + texcl + vals[p];
        cur[i] = e;
        rs[b * RBF + i] = e;
    }
    __syncthreads();
    for (unsigned i = start + t; i < end; i += 256) {
        const uint2 r = recs[i];
        const unsigned slot = atomicAdd(&cur[r.y & (RBF - 1u)], 1u);
        recf[slot] = r.x;
    }
}

// ---------------- S5: one wave per dst row, register accumulation ----------
__global__ __launch_bounds__(256) void s_accum4(
    const __half* __restrict__ in_feat, const unsigned* __restrict__ recf,
    const unsigned* __restrict__ rs, float* __restrict__ h,
    int NROWS, int totalWaves)
{
    const int lane = threadIdx.x & 63;
    const int wid = (int)((blockIdx.x * (size_t)blockDim.x + threadIdx.x) >> 6);

    for (int row = wid; row < NROWS; row += totalWaves) {
        const unsigned s = rs[row], e = rs[row + 1];
        float acc = 0.0f;
        unsigned done = s;
        while (done < e) {
            const int c = (int)min(64u, e - done);
            unsigned rcd = 0u;
            if (lane < c) rcd = recf[done + lane];   // coalesced 4B x c
            for (int j0 = 0; j0 < c; j0 += GU) {
                float v[GU], wj[GU];
                #pragma unroll
                for (int jj = 0; jj < GU; ++jj) {
                    const int idx = j0 + jj;
                    const int cl  = (idx < c) ? idx : (c - 1);
                    const unsigned px =
                        (unsigned)__builtin_amdgcn_readlane((int)rcd, cl);
                    v[jj]  = __half2float(
                        in_feat[((size_t)(px & 0x3FFFFu) << 6) + lane]);
                    wj[jj] = (idx < c) ? (float)(px >> 18) : 0.0f;
                }
                #pragma unroll
                for (int jj = 0; jj < GU; ++jj) acc = fmaf(v[jj], wj[jj], acc);
            }
            done += (unsigned)c;
        }
        h[((size_t)row << 6) + lane] = acc * (1.0f / WQS);
    }
}

// ---------------- fallback K2 (atomic scatter) ----------------------------
#define K2_U 8
__global__ __launch_bounds__(256) void k_edges(
    const __half* __restrict__ in_feat, const int* __restrict__ esrc,
    const int* __restrict__ edst, const float* __restrict__ ew,
    float* __restrict__ h, int E, int totalWaves)
{
    const int lane = threadIdx.x & 63;
    int wid = (int)((blockIdx.x * (size_t)blockDim.x + threadIdx.x) >> 6);
    wid = __builtin_amdgcn_readfirstlane(wid);
    const int chunk = (E + totalWaves - 1) / totalWaves;
    int e0 = wid * chunk;
    int e1 = min(e0 + chunk, E);
    for (int base = e0; base < e1; base += K2_U) {
        const int nb = min(K2_U, e1 - base);
        int s[K2_U], d[K2_U]; float w[K2_U];
        #pragma unroll
        for (int j = 0; j < K2_U; ++j) {
            int idx = base + ((j < nb) ? j : 0);
            s[j] = esrc[idx]; d[j] = edst[idx]; w[j] = ew[idx];
        }
        float v[K2_U];
        #pragma unroll
        for (int j = 0; j < K2_U; ++j)
            v[j] = __half2float(in_feat[((size_t)s[j] << 6) + lane]);
        #pragma unroll
        for (int j = 0; j < K2_U; ++j)
            if (j < nb) atomicAdd(h + ((size_t)d[j] << 6) + lane, v[j] * w[j]);
    }
}

// ---------------- K3: activation + pool + two GEMVs + l2norm --------------
__global__ __launch_bounds__(256) void k_finalize(
    const float* __restrict__ h, const float* __restrict__ bias,
    const float* __restrict__ prelu_a,
    const float* __restrict__ w_sub, const float* __restrict__ b_sub,
    const float* __restrict__ w_gcn, const float* __restrict__ b_gcn,
    float* __restrict__ out_sub, float* __restrict__ out_gcn,
    int G, int totalWaves)
{
    const int lane = threadIdx.x & 63;
    const int wid = (int)((blockIdx.x * (size_t)blockDim.x + threadIdx.x) >> 6);

    float wsreg[64], wgreg[64];
    #pragma unroll
    for (int k = 0; k < 64; ++k) wsreg[k] = w_sub[lane * 64 + k];
    #pragma unroll
    for (int k = 0; k < 64; ++k) wgreg[k] = w_gcn[lane * 64 + k];
    const float bj  = bias[lane];
    const float bsj = b_sub[lane];
    const float bgj = b_gcn[lane];
    const float a   = prelu_a[0];

    for (int g = wid; g < G; g += totalWaves) {
        const float* hp = h + (size_t)g * 256;
        float p0 = preluf(hp[lane]       + bj, a);
        float p1 = preluf(hp[64  + lane] + bj, a);
        float p2 = preluf(hp[128 + lane] + bj, a);
        float p3 = preluf(hp[192 + lane] + bj, a);
        float pool = (p0 + p1 + p2 + p3) * 0.25f;
        float gcn  = p0;

        float as = bsj, ag = bgj;
        #pragma unroll
        for (int k = 0; k < 64; ++k) {
            as = fmaf(rdlane(pool, k), wsreg[k], as);
            ag = fmaf(rdlane(gcn,  k), wgreg[k], ag);
        }
        float ss = as * as, sg = ag * ag;
        #pragma unroll
        for (int off = 32; off >= 1; off >>= 1) {
            ss += __shfl_xor(ss, off, 64);
            sg += __shfl_xor(sg, off, 64);
        }
        out_sub[(size_t)g * 64 + lane] = as / fmaxf(sqrtf(ss), EPSN);
        out_gcn[(size_t)g * 64 + lane] = ag / fmaxf(sqrtf(sg), EPSN);
    }
}

extern "C" void kernel_launch(void* const* d_in, const int* in_sizes, int n_in,
                              void* d_out, int out_size, void* d_ws, size_t ws_size,
                              hipStream_t stream)
{
    const float* feat    = (const float*)d_in[0];
    const int*   esrc    = (const int*)  d_in[1];
    const int*   edst    = (const int*)  d_in[2];
    const float* ew      = (const float*)d_in[3];
    const float* weight  = (const float*)d_in[4];
    const float* bias    = (const float*)d_in[5];
    const float* prelu_a = (const float*)d_in[6];
    const float* w_sub   = (const float*)d_in[7];
    const float* b_sub   = (const float*)d_in[8];
    const float* w_gcn   = (const float*)d_in[9];
    const float* b_gcn   = (const float*)d_in[10];

    const int N = in_sizes[0] / 128;
    const int E = in_sizes[1];
    const int G = N / 4;
    const int nwg = (E + CHK - 1) / CHK;

    // ws layout (sorted path; bytes). AH = N*64*2 (fp16), A = N*64*4:
    //   in_feat : [0, AH)
    //   h       : [AH, AH+A)     -- written by s_accum4 (after sortfine)
    //   recs    : [AH, AH+E*8)   -- overlays h; dead before s_accum4 runs
    //   recf    : [AH+A, +E*4)
    //   C       : nwg*NBC*4         (scanned IN PLACE)
    //   T       : NBC*4
    //   basep   : (NBC+1)*4
    //   rs      : (N+1)*4
    char* wsb = (char*)d_ws;
    const size_t AH    = (size_t)N * 64 * 2;
    const size_t A     = (size_t)N * 64 * 4;
    const size_t offRf = AH + A;
    const size_t offC  = offRf + (size_t)E * 4;
    const size_t offT  = offC  + (size_t)nwg * NBC * 4;
    const size_t offBp = offT  + (size_t)NBC * 4;
    const size_t offRs = offBp + (size_t)(NBC + 1) * 4;
    const size_t ws_need = offRs + (size_t)(N + 1) * 4;

    __half*   in_feat = (__half*)wsb;
    float*    h       = (float*)(wsb + AH);
    uint2*    recs    = (uint2*)(wsb + AH);
    unsigned* recf    = (unsigned*)(wsb + offRf);
    unsigned* C       = (unsigned*)(wsb + offC);
    unsigned* T       = (unsigned*)(wsb + offT);
    unsigned* basep   = (unsigned*)(wsb + offBp);
    unsigned* rs      = (unsigned*)(wsb + offRs);

    float* out        = (float*)d_out;
    float* out_sub    = out;
    float* out_anchor = out + (size_t)G * 64;
    float* out_gcn    = out + (size_t)2 * G * 64;

    const bool sorted_path =
        (N == NBC * RBF) && (nwg <= NWGMAX) && ((size_t)E * 8 <= A) &&
        (ws_size >= ws_need);

    {   // K1: MFMA when the shape allows, VALU fallback otherwise
        const int blocks = 1024, tw = blocks * 4;
        if ((N & 15) == 0)
            k_mfma<<<blocks, 256, 0, stream>>>(feat, weight, bias, prelu_a,
                                               in_feat, out_anchor, N, tw);
        else
            k_transform2<<<blocks, 256, 0, stream>>>(feat, weight, bias, prelu_a,
                                                     in_feat, out_anchor, N, tw);
    }

    if (sorted_path) {
        s_count2  <<<nwg, 256, 0, stream>>>(esrc, edst, E, C);
        s_scanA   <<<NBC, 256, 0, stream>>>(C, T, nwg);
        s_scanB   <<<1, 256, 0, stream>>>(T, basep, rs, N);
        s_scatter4<<<nwg, 256, 0, stream>>>(esrc, edst, ew, E, basep, C, T,
                                            nwg, recs);
        s_sortfine<<<NBC, 256, 0, stream>>>(recs, basep, recf, rs);
        {
            const int blocks = 2048, tw = blocks * 4;   // 8192 waves, 32 rows each
            s_accum4<<<blocks, 256, 0, stream>>>(in_feat, recf, rs, h, N, tw);
        }
        {
            const int blocks = 4096, tw = blocks * 4;
            k_finalize<<<blocks, 256, 0, stream>>>(h, bias, prelu_a, w_sub, b_sub,
                                                   w_gcn, b_gcn, out_sub, out_gcn, G, tw);
        }
    } else if (ws_size >= AH + A) {
        hipMemsetAsync(h, 0, A, stream);
        const int blocks = 2048, tw = blocks * 4;
        k_edges<<<blocks, 256, 0, stream>>>(in_feat, esrc, edst, ew, h, E, tw);
        const int fblocks = 4096, ftw = fblocks * 4;
        k_finalize<<<fblocks, 256, 0, stream>>>(h, bias, prelu_a, w_sub, b_sub,
                                                w_gcn, b_gcn, out_sub, out_gcn, G, ftw);
    }
}

// Round 9
// 481.407 us; speedup vs baseline: 1.3122x; 1.0775x over previous
//
#include <hip/hip_runtime.h>
#include <hip/hip_fp16.h>

#define EPSN 1e-12f
#define NBC  256             // coarse dst buckets (dst >> 10), 1024 rows each
#define RBF  1024            // rows per coarse bucket
#define CHK  8192            // edges per count/scatter workgroup (nwg = 512)
#define NWGMAX 1024          // scanA handles up to 4 block-counts per thread
#define PU   4               // edge-PAIRS in flight per wave in accumulate
#define WQS  16384.0f        // weight quantization scale (14 bits)

typedef _Float16 half8_t __attribute__((ext_vector_type(8)));
typedef float    f32x4  __attribute__((ext_vector_type(4)));

__device__ __forceinline__ float rdlane(float v, int k) {
    return __int_as_float(__builtin_amdgcn_readlane(__float_as_int(v), k));
}
__device__ __forceinline__ float preluf(float x, float a) {
    return x >= 0.0f ? x : a * x;
}

// ---------------- transform body (MFMA): in_feat(fp16) = feat_z @ weight ---
// Wave owns 16 rows x 64 cols: 4 C-tiles, K=128 in 4 MFMA steps. B-frags
// hoisted to VGPRs. A/B share the same (lane,e)->k map so the K permutation
// cancels; C layout col=lane&15, row=(lane>>4)*4+reg (verified).
__device__ __forceinline__ void transform_body(
    const float* __restrict__ feat, const float* __restrict__ weight,
    const float* __restrict__ bias, const float* __restrict__ prelu_a,
    __half* __restrict__ in_feat, float* __restrict__ out_anchor,
    int N, int wid, int totalWaves)
{
    const int lane = threadIdx.x & 63;
    const int r    = lane & 15;
    const int g    = lane >> 4;
    const int nt4  = N >> 4;

    half8_t bfr[4][4];
    #pragma unroll
    for (int nt = 0; nt < 4; ++nt)
        #pragma unroll
        for (int kq = 0; kq < 4; ++kq)
            #pragma unroll
            for (int e = 0; e < 8; ++e)
                bfr[nt][kq][e] =
                    (_Float16)weight[(kq * 32 + g * 8 + e) * 64 + nt * 16 + r];

    float bj[4];
    #pragma unroll
    for (int nt = 0; nt < 4; ++nt) bj[nt] = bias[nt * 16 + r];
    const float a = prelu_a[0];

    for (int t = wid; t < nt4; t += totalWaves) {
        const int rb = t << 4;

        f32x4 acc[4];
        #pragma unroll
        for (int nt = 0; nt < 4; ++nt) acc[nt] = (f32x4){0.f, 0.f, 0.f, 0.f};

        const float* fr = feat + (size_t)(rb + r) * 128 + g * 8;
        #pragma unroll
        for (int kq = 0; kq < 4; ++kq) {
            const float4 f0 = *(const float4*)(fr + kq * 32);
            const float4 f1 = *(const float4*)(fr + kq * 32 + 4);
            half8_t af;
            af[0] = (_Float16)f0.x; af[1] = (_Float16)f0.y;
            af[2] = (_Float16)f0.z; af[3] = (_Float16)f0.w;
            af[4] = (_Float16)f1.x; af[5] = (_Float16)f1.y;
            af[6] = (_Float16)f1.z; af[7] = (_Float16)f1.w;
            #pragma unroll
            for (int nt = 0; nt < 4; ++nt)
                acc[nt] = __builtin_amdgcn_mfma_f32_16x16x32_f16(
                    af, bfr[nt][kq], acc[nt], 0, 0, 0);
        }

        const int row0 = rb + g * 4;       // reg 0 rows are the anchors
        float ss = 0.0f, y[4];
        #pragma unroll
        for (int nt = 0; nt < 4; ++nt) {
            y[nt] = preluf(acc[nt][0] + bj[nt], a);
            ss = fmaf(y[nt], y[nt], ss);
        }
        ss += __shfl_xor(ss, 1, 16);
        ss += __shfl_xor(ss, 2, 16);
        ss += __shfl_xor(ss, 4, 16);
        ss += __shfl_xor(ss, 8, 16);
        const float inv = 1.0f / fmaxf(sqrtf(ss), EPSN);
        #pragma unroll
        for (int nt = 0; nt < 4; ++nt)
            out_anchor[(size_t)(row0 >> 2) * 64 + nt * 16 + r] = y[nt] * inv;
        #pragma unroll
        for (int nt = 0; nt < 4; ++nt)
            in_feat[(size_t)row0 * 64 + nt * 16 + r] = __float2half(0.0f);
        #pragma unroll
        for (int reg = 1; reg < 4; ++reg)
            #pragma unroll
            for (int nt = 0; nt < 4; ++nt)
                in_feat[(size_t)(row0 + reg) * 64 + nt * 16 + r] =
                    __float2half(acc[nt][reg]);
    }
}

// ---------------- fused K1 + S1: transform || per-block histograms ---------
// Independent work; count's LDS atomics hide under transform's memory time.
__global__ __launch_bounds__(256) void k_tc(
    const float* __restrict__ feat, const float* __restrict__ weight,
    const float* __restrict__ bias, const float* __restrict__ prelu_a,
    __half* __restrict__ in_feat, float* __restrict__ out_anchor, int N,
    int nbT, int twT,
    const int* __restrict__ esrc, const int* __restrict__ edst, int E,
    unsigned* __restrict__ C)
{
    __shared__ unsigned hist[NBC];
    const int t = threadIdx.x;
    if ((int)blockIdx.x < nbT) {
        const int wid = (int)((blockIdx.x * (size_t)blockDim.x + t) >> 6);
        transform_body(feat, weight, bias, prelu_a, in_feat, out_anchor,
                       N, wid, twT);
        return;
    }
    const int blk = (int)blockIdx.x - nbT;
    hist[t] = 0;
    __syncthreads();
    const int base = blk * CHK;
    for (int r = 0; r < CHK / (16 * 256); ++r) {
        int d[16];
        #pragma unroll
        for (int i = 0; i < 16; ++i) {
            const int idx = base + (r * 16 + i) * 256 + t;
            d[i] = -1;
            if (idx < E) {
                const int s = esrc[idx];
                if ((s & 3) != 0) d[i] = edst[idx];   // drop zero-msg edges
            }
        }
        #pragma unroll
        for (int i = 0; i < 16; ++i)
            if (d[i] >= 0) atomicAdd(&hist[((unsigned)d[i]) >> 10], 1u);
    }
    __syncthreads();
    C[(size_t)blk * NBC + t] = hist[t];
}

// ---------------- S2: per-bucket exclusive scan over blocks, IN PLACE ------
__global__ __launch_bounds__(256) void s_scanA(
    unsigned* __restrict__ C, unsigned* __restrict__ T, int nwg)
{
    __shared__ unsigned ssum[256];
    const int i = blockIdx.x;
    const int t = threadIdx.x;
    const int PER = (nwg + 255) / 256;           // <= 4
    unsigned vals[4];
    unsigned run = 0;
    for (int p = 0; p < PER; ++p) {
        const int blk = t * PER + p;
        const unsigned v = (blk < nwg) ? C[(size_t)blk * NBC + i] : 0u;
        vals[p] = run;
        run += v;
    }
    ssum[t] = run;
    __syncthreads();
    for (int off = 1; off < 256; off <<= 1) {
        unsigned x = (t >= off) ? ssum[t - off] : 0u;
        __syncthreads();
        ssum[t] += x;
        __syncthreads();
    }
    const unsigned texcl = ssum[t] - run;
    for (int p = 0; p < PER; ++p) {
        const int blk = t * PER + p;
        if (blk < nwg) C[(size_t)blk * NBC + i] = texcl + vals[p];
    }
    if (t == 255) T[i] = ssum[255];
}

// ---------------- S3: block-local counting sort + coalesced flush ----------
// bucket bases recomputed from T in-prologue (scanB kernel deleted).
// record: x = src(18) | wq(14), y = dst.
__global__ __launch_bounds__(256) void s_scatter4(
    const int* __restrict__ esrc, const int* __restrict__ edst,
    const float* __restrict__ ew, int E,
    const unsigned* __restrict__ C, const unsigned* __restrict__ T, int nwg,
    uint2* __restrict__ recs)
{
    __shared__ uint2    buf[CHK];        // 64 KB
    __shared__ unsigned cur[NBC];
    __shared__ unsigned cb [NBC];
    __shared__ unsigned ssum[256];
    const int blk = blockIdx.x;
    const int t   = threadIdx.x;

    // exclusive scan of T -> per-bucket global base
    const unsigned Tt = T[t];
    ssum[t] = Tt;
    __syncthreads();
    for (int off = 1; off < 256; off <<= 1) {
        unsigned x = (t >= off) ? ssum[t - off] : 0u;
        __syncthreads();
        ssum[t] += x;
        __syncthreads();
    }
    const unsigned basepl = ssum[t] - Tt;
    __syncthreads();

    // this block's per-bucket count + local scan
    const unsigned own = C[(size_t)blk * NBC + t];
    const unsigned nxt = (blk + 1 < nwg) ? C[(size_t)(blk + 1) * NBC + t] : Tt;
    const unsigned myc = nxt - own;
    ssum[t] = myc;
    __syncthreads();
    for (int off = 1; off < 256; off <<= 1) {
        unsigned x = (t >= off) ? ssum[t - off] : 0u;
        __syncthreads();
        ssum[t] += x;
        __syncthreads();
    }
    const unsigned excl = ssum[t] - myc;
    cur[t] = excl;
    cb[t]  = basepl + own - excl;        // unsigned wrap ok
    __syncthreads();
    const unsigned cnt = ssum[255];

    const int base = blk * CHK;
    for (int r = 0; r < CHK / (16 * 256); ++r) {
        int s[16], d[16]; float wv[16];
        #pragma unroll
        for (int i = 0; i < 16; ++i) {
            const int idx = base + (r * 16 + i) * 256 + t;
            const bool ok = (idx < E);
            s[i]  = ok ? esrc[idx] : 0;
            d[i]  = ok ? edst[idx] : 0;
            wv[i] = ok ? ew[idx]   : 0.0f;
            if (!ok || (s[i] & 3) == 0) d[i] = -1;
        }
        #pragma unroll
        for (int i = 0; i < 16; ++i) {
            if (d[i] >= 0) {
                const unsigned slot = atomicAdd(&cur[((unsigned)d[i]) >> 10], 1u);
                const unsigned wq =
                    min((unsigned)(wv[i] * WQS + 0.5f), 16383u);
                buf[slot] = make_uint2(((unsigned)s[i]) | (wq << 18),
                                       (unsigned)d[i]);
            }
        }
    }
    __syncthreads();
    for (unsigned i = t; i < cnt; i += 256) {      // coalesced flush
        const uint2 rr = buf[i];
        recs[cb[rr.y >> 10] + i] = rr;
    }
}

// ---------------- S4: per-bucket fine sort (1024 rows) -> 4B records -------
__global__ __launch_bounds__(256) void s_sortfine(
    const uint2* __restrict__ recs, const unsigned* __restrict__ T,
    unsigned* __restrict__ recf, unsigned* __restrict__ rs, int N)
{
    __shared__ unsigned hist[RBF], cur[RBF], ssum[256];
    const int t = threadIdx.x;
    const int b = blockIdx.x;

    // bucket start/end from scan of T
    const unsigned Tt = T[t];
    ssum[t] = Tt;
    __syncthreads();
    for (int off = 1; off < 256; off <<= 1) {
        unsigned x = (t >= off) ? ssum[t - off] : 0u;
        __syncthreads();
        ssum[t] += x;
        __syncthreads();
    }
    const unsigned start = (b == 0) ? 0u : ssum[b - 1];
    const unsigned end   = ssum[b];
    if (b == NBC - 1 && t == 0) rs[N] = ssum[NBC - 1];
    __syncthreads();

    #pragma unroll
    for (int p = 0; p < 4; ++p) hist[t * 4 + p] = 0;
    __syncthreads();
    for (unsigned i = start + t; i < end; i += 256)
        atomicAdd(&hist[recs[i].y & (RBF - 1u)], 1u);
    __syncthreads();
    unsigned vals[4], run = 0;
    #pragma unroll
    for (int p = 0; p < 4; ++p) { vals[p] = run; run += hist[t * 4 + p]; }
    ssum[t] = run;
    __syncthreads();
    for (int off = 1; off < 256; off <<= 1) {
        unsigned x = (t >= off) ? ssum[t - off] : 0u;
        __syncthreads();
        ssum[t] += x;
        __syncthreads();
    }
    const unsigned texcl = ssum[t] - run;
    #pragma unroll
    for (int p = 0; p < 4; ++p) {
        const int i = t * 4 + p;
        const unsigned e = start + texcl + vals[p];
        cur[i] = e;
        rs[b * RBF + i] = e;
    }
    __syncthreads();
    for (unsigned i = start + t; i < end; i += 256) {
        const uint2 r = recs[i];
        const unsigned slot = atomicAdd(&cur[r.y & (RBF - 1u)], 1u);
        recf[slot] = r.x;
    }
}

// ---------------- S5 v2: paired-edge gather, 2 cols/lane -------------------
// R8: VALUBusy 77% (issue-bound, ~8-10 VALU/edge). Here lanes 0-31 process
// edge 2p, lanes 32-63 edge 2p+1; each lane loads a __half2 (2 cols). Record
// broadcast via one __shfl (DS pipe); 32-bit voffset (saddr form); dummy
// slots carry rcd=0 -> src 0 (anchor row, zeros) and wq=0, so no per-edge
// bounds cndmask. ~7 VALU + 1 DS + 1 VMEM per PAIR.
__global__ __launch_bounds__(256) void s_accum5(
    const __half* __restrict__ in_feat, const unsigned* __restrict__ recf,
    const unsigned* __restrict__ rs, float* __restrict__ h,
    int NROWS, int totalWaves)
{
    const char* ifb  = (const char*)in_feat;
    const int   lane = threadIdx.x & 63;
    const int   l32  = lane & 31;
    const int   hsel = lane >> 5;                 // 0: even edge, 1: odd edge
    const unsigned colb = (unsigned)l32 * 4u;     // byte offset of col pair
    const int wid = (int)((blockIdx.x * (size_t)blockDim.x + threadIdx.x) >> 6);

    for (int row = wid; row < NROWS; row += totalWaves) {
        const unsigned s = rs[row], e = rs[row + 1];
        float acc0 = 0.0f, acc1 = 0.0f;
        for (unsigned done = s; done < e; done += 64u) {
            const int c = (int)min(64u, e - done);
            unsigned rcd = 0u;
            if (lane < c) rcd = recf[done + lane];   // coalesced 4B x c
            const int pairs = (c + 1) >> 1;
            for (int p0 = 0; p0 < pairs; p0 += PU) {
                unsigned px[PU];
                __half2  hh[PU];
                float    wj[PU];
                #pragma unroll
                for (int pp = 0; pp < PU; ++pp) {
                    const int jv = (p0 + pp) * 2 + hsel;      // 1 v_add
                    px[pp] = (unsigned)__shfl((int)rcd, jv, 64);
                }
                #pragma unroll
                for (int pp = 0; pp < PU; ++pp) {
                    const unsigned voff =
                        ((px[pp] & 0x3FFFFu) << 7) + colb;    // and + lshl_add
                    hh[pp] = *(const __half2*)(ifb + (size_t)voff);
                    wj[pp] = (float)(px[pp] >> 18);           // lshr + cvt
                }
                #pragma unroll
                for (int pp = 0; pp < PU; ++pp) {
                    acc0 = fmaf(__half2float(__low2half(hh[pp])),  wj[pp], acc0);
                    acc1 = fmaf(__half2float(__high2half(hh[pp])), wj[pp], acc1);
                }
            }
        }
        acc0 += __shfl_xor(acc0, 32, 64);
        acc1 += __shfl_xor(acc1, 32, 64);
        if (hsel == 0) {
            float2 o;
            o.x = acc0 * (1.0f / WQS);
            o.y = acc1 * (1.0f / WQS);
            *(float2*)(h + ((size_t)row << 6) + 2 * l32) = o;
        }
    }
}

// ---------------- K1 fallback (VALU, row-per-lane) -------------------------
__global__ __launch_bounds__(256) void k_transform2(
    const float* __restrict__ feat, const float* __restrict__ weight,
    const float* __restrict__ bias, const float* __restrict__ prelu_a,
    __half* __restrict__ in_feat, float* __restrict__ out_anchor,
    int N, int totalWaves)
{
    const int lane  = threadIdx.x & 63;
    const int wid   = (int)((blockIdx.x * (size_t)blockDim.x + threadIdx.x) >> 6);
    const int tiles = (N + 63) >> 6;

    for (int tile = wid; tile < tiles; tile += totalWaves) {
        const int row = tile * 64 + lane;
        if (row >= N) continue;

        float acc[64];
        #pragma unroll
        for (int j = 0; j < 64; ++j) acc[j] = 0.0f;

        const float4* fp = (const float4*)(feat + (size_t)row * 128);
        #pragma unroll 4
        for (int kc = 0; kc < 32; ++kc) {
            const float4 f = fp[kc];
            const float fs[4] = {f.x, f.y, f.z, f.w};
            #pragma unroll
            for (int kk = 0; kk < 4; ++kk) {
                const float fv = fs[kk];
                const float* wr = weight + (kc * 4 + kk) * 64;
                #pragma unroll
                for (int j = 0; j < 64; ++j)
                    acc[j] = fmaf(fv, wr[j], acc[j]);
            }
        }

        if ((row & 3) == 0) {
            const float a = prelu_a[0];
            float ss = 0.0f;
            #pragma unroll
            for (int j = 0; j < 64; ++j) {
                acc[j] = preluf(acc[j] + bias[j], a);
                ss = fmaf(acc[j], acc[j], ss);
            }
            const float inv = 1.0f / fmaxf(sqrtf(ss), EPSN);
            float* ap = out_anchor + (size_t)(row >> 2) * 64;
            #pragma unroll
            for (int j = 0; j < 64; ++j) ap[j] = acc[j] * inv;
            #pragma unroll
            for (int j = 0; j < 64; ++j)
                in_feat[(size_t)row * 64 + j] = __float2half(0.0f);
        } else {
            #pragma unroll
            for (int j = 0; j < 64; ++j)
                in_feat[(size_t)row * 64 + j] = __float2half(acc[j]);
        }
    }
}

// ---------------- fallback K2 (atomic scatter) ----------------------------
#define K2_U 8
__global__ __launch_bounds__(256) void k_edges(
    const __half* __restrict__ in_feat, const int* __restrict__ esrc,
    const int* __restrict__ edst, const float* __restrict__ ew,
    float* __restrict__ h, int E, int totalWaves)
{
    const int lane = threadIdx.x & 63;
    int wid = (int)((blockIdx.x * (size_t)blockDim.x + threadIdx.x) >> 6);
    wid = __builtin_amdgcn_readfirstlane(wid);
    const int chunk = (E + totalWaves - 1) / totalWaves;
    int e0 = wid * chunk;
    int e1 = min(e0 + chunk, E);
    for (int base = e0; base < e1; base += K2_U) {
        const int nb = min(K2_U, e1 - base);
        int s[K2_U], d[K2_U]; float w[K2_U];
        #pragma unroll
        for (int j = 0; j < K2_U; ++j) {
            int idx = base + ((j < nb) ? j : 0);
            s[j] = esrc[idx]; d[j] = edst[idx]; w[j] = ew[idx];
        }
        float v[K2_U];
        #pragma unroll
        for (int j = 0; j < K2_U; ++j)
            v[j] = __half2float(in_feat[((size_t)s[j] << 6) + lane]);
        #pragma unroll
        for (int j = 0; j < K2_U; ++j)
            if (j < nb) atomicAdd(h + ((size_t)d[j] << 6) + lane, v[j] * w[j]);
    }
}

// ---------------- K3: activation + pool + two GEMVs + l2norm --------------
__global__ __launch_bounds__(256) void k_finalize(
    const float* __restrict__ h, const float* __restrict__ bias,
    const float* __restrict__ prelu_a,
    const float* __restrict__ w_sub, const float* __restrict__ b_sub,
    const float* __restrict__ w_gcn, const float* __restrict__ b_gcn,
    float* __restrict__ out_sub, float* __restrict__ out_gcn,
    int G, int totalWaves)
{
    const int lane = threadIdx.x & 63;
    const int wid = (int)((blockIdx.x * (size_t)blockDim.x + threadIdx.x) >> 6);

    float wsreg[64], wgreg[64];
    #pragma unroll
    for (int k = 0; k < 64; ++k) wsreg[k] = w_sub[lane * 64 + k];
    #pragma unroll
    for (int k = 0; k < 64; ++k) wgreg[k] = w_gcn[lane * 64 + k];
    const float bj  = bias[lane];
    const float bsj = b_sub[lane];
    const float bgj = b_gcn[lane];
    const float a   = prelu_a[0];

    for (int g = wid; g < G; g += totalWaves) {
        const float* hp = h + (size_t)g * 256;
        float p0 = preluf(hp[lane]       + bj, a);
        float p1 = preluf(hp[64  + lane] + bj, a);
        float p2 = preluf(hp[128 + lane] + bj, a);
        float p3 = preluf(hp[192 + lane] + bj, a);
        float pool = (p0 + p1 + p2 + p3) * 0.25f;
        float gcn  = p0;

        float as = bsj, ag = bgj;
        #pragma unroll
        for (int k = 0; k < 64; ++k) {
            as = fmaf(rdlane(pool, k), wsreg[k], as);
            ag = fmaf(rdlane(gcn,  k), wgreg[k], ag);
        }
        float ss = as * as, sg = ag * ag;
        #pragma unroll
        for (int off = 32; off >= 1; off >>= 1) {
            ss += __shfl_xor(ss, off, 64);
            sg += __shfl_xor(sg, off, 64);
        }
        out_sub[(size_t)g * 64 + lane] = as / fmaxf(sqrtf(ss), EPSN);
        out_gcn[(size_t)g * 64 + lane] = ag / fmaxf(sqrtf(sg), EPSN);
    }
}

extern "C" void kernel_launch(void* const* d_in, const int* in_sizes, int n_in,
                              void* d_out, int out_size, void* d_ws, size_t ws_size,
                              hipStream_t stream)
{
    const float* feat    = (const float*)d_in[0];
    const int*   esrc    = (const int*)  d_in[1];
    const int*   edst    = (const int*)  d_in[2];
    const float* ew      = (const float*)d_in[3];
    const float* weight  = (const float*)d_in[4];
    const float* bias    = (const float*)d_in[5];
    const float* prelu_a = (const float*)d_in[6];
    const float* w_sub   = (const float*)d_in[7];
    const float* b_sub   = (const float*)d_in[8];
    const float* w_gcn   = (const float*)d_in[9];
    const float* b_gcn   = (const float*)d_in[10];

    const int N = in_sizes[0] / 128;
    const int E = in_sizes[1];
    const int G = N / 4;
    const int nwg = (E + CHK - 1) / CHK;

    // ws layout (sorted path; bytes). AH = N*64*2 (fp16), A = N*64*4:
    //   in_feat : [0, AH)
    //   h       : [AH, AH+A)     -- written by s_accum5 (after sortfine)
    //   recs    : [AH, AH+E*8)   -- overlays h; dead before s_accum5 runs
    //   recf    : [AH+A, +E*4)
    //   C       : nwg*NBC*4         (scanned IN PLACE)
    //   T       : NBC*4
    //   rs      : (N+1)*4
    char* wsb = (char*)d_ws;
    const size_t AH    = (size_t)N * 64 * 2;
    const size_t A     = (size_t)N * 64 * 4;
    const size_t offRf = AH + A;
    const size_t offC  = offRf + (size_t)E * 4;
    const size_t offT  = offC  + (size_t)nwg * NBC * 4;
    const size_t offRs = offT  + (size_t)NBC * 4;
    const size_t ws_need = offRs + (size_t)(N + 1) * 4;

    __half*   in_feat = (__half*)wsb;
    float*    h       = (float*)(wsb + AH);
    uint2*    recs    = (uint2*)(wsb + AH);
    unsigned* recf    = (unsigned*)(wsb + offRf);
    unsigned* C       = (unsigned*)(wsb + offC);
    unsigned* T       = (unsigned*)(wsb + offT);
    unsigned* rs      = (unsigned*)(wsb + offRs);

    float* out        = (float*)d_out;
    float* out_sub    = out;
    float* out_anchor = out + (size_t)G * 64;
    float* out_gcn    = out + (size_t)2 * G * 64;

    const bool sorted_path =
        (N == NBC * RBF) && (nwg <= NWGMAX) && ((size_t)E * 8 <= A) &&
        (ws_size >= ws_need);

    if (sorted_path) {
        {   // fused transform (1024 blocks) + count (nwg blocks)
            const int nbT = 1024, twT = nbT * 4;
            k_tc<<<nbT + nwg, 256, 0, stream>>>(feat, weight, bias, prelu_a,
                                                in_feat, out_anchor, N, nbT, twT,
                                                esrc, edst, E, C);
        }
        s_scanA   <<<NBC, 256, 0, stream>>>(C, T, nwg);
        s_scatter4<<<nwg, 256, 0, stream>>>(esrc, edst, ew, E, C, T, nwg, recs);
        s_sortfine<<<NBC, 256, 0, stream>>>(recs, T, recf, rs, N);
        {
            const int blocks = 2048, tw = blocks * 4;   // 8192 waves, 32 rows each
            s_accum5<<<blocks, 256, 0, stream>>>(in_feat, recf, rs, h, N, tw);
        }
        {
            const int blocks = 4096, tw = blocks * 4;
            k_finalize<<<blocks, 256, 0, stream>>>(h, bias, prelu_a, w_sub, b_sub,
                                                   w_gcn, b_gcn, out_sub, out_gcn, G, tw);
        }
    } else if (ws_size >= AH + A) {
        {
            const int blocks = 1024, tw = blocks * 4;
            k_transform2<<<blocks, 256, 0, stream>>>(feat, weight, bias, prelu_a,
                                                     in_feat, out_anchor, N, tw);
        }
        hipMemsetAsync(h, 0, A, stream);
        const int blocks = 2048, tw = blocks * 4;
        k_edges<<<blocks, 256, 0, stream>>>(in_feat, esrc, edst, ew, h, E, tw);
        const int fblocks = 4096, ftw = fblocks * 4;
        k_finalize<<<fblocks, 256, 0, stream>>>(h, bias, prelu_a, w_sub, b_sub,
                                                w_gcn, b_gcn, out_sub, out_gcn, G, ftw);
    }
}

// Round 10
// 462.056 us; speedup vs baseline: 1.3672x; 1.0419x over previous
//
#include <hip/hip_runtime.h>
#include <hip/hip_fp16.h>

#define EPSN 1e-12f
#define NBC  256             // coarse dst buckets (dst >> 10), 1024 rows each
#define RBF  1024            // rows per coarse bucket
#define CHK  8192            // edges per count/scatter workgroup (nwg = 512)
#define NWGMAX 1024          // scanA handles up to 4 block-counts per thread
#define PU   4               // edge-PAIRS in flight per wave in accumulate
#define WQS  16384.0f        // weight quantization scale (14 bits)

typedef _Float16 half8_t __attribute__((ext_vector_type(8)));
typedef float    f32x4  __attribute__((ext_vector_type(4)));

__device__ __forceinline__ float rdlane(float v, int k) {
    return __int_as_float(__builtin_amdgcn_readlane(__float_as_int(v), k));
}
__device__ __forceinline__ float preluf(float x, float a) {
    return x >= 0.0f ? x : a * x;
}

// ---------------- transform body (MFMA): in_feat(fp16) = feat_z @ weight ---
// Wave owns 16 rows x 64 cols: 4 C-tiles, K=128 in 4 MFMA steps. B-frags
// hoisted to VGPRs. A/B share the same (lane,e)->k map so the K permutation
// cancels; C layout col=lane&15, row=(lane>>4)*4+reg (verified).
__device__ __forceinline__ void transform_body(
    const float* __restrict__ feat, const float* __restrict__ weight,
    const float* __restrict__ bias, const float* __restrict__ prelu_a,
    __half* __restrict__ in_feat, float* __restrict__ out_anchor,
    int N, int wid, int totalWaves)
{
    const int lane = threadIdx.x & 63;
    const int r    = lane & 15;
    const int g    = lane >> 4;
    const int nt4  = N >> 4;

    half8_t bfr[4][4];
    #pragma unroll
    for (int nt = 0; nt < 4; ++nt)
        #pragma unroll
        for (int kq = 0; kq < 4; ++kq)
            #pragma unroll
            for (int e = 0; e < 8; ++e)
                bfr[nt][kq][e] =
                    (_Float16)weight[(kq * 32 + g * 8 + e) * 64 + nt * 16 + r];

    float bj[4];
    #pragma unroll
    for (int nt = 0; nt < 4; ++nt) bj[nt] = bias[nt * 16 + r];
    const float a = prelu_a[0];

    for (int t = wid; t < nt4; t += totalWaves) {
        const int rb = t << 4;

        f32x4 acc[4];
        #pragma unroll
        for (int nt = 0; nt < 4; ++nt) acc[nt] = (f32x4){0.f, 0.f, 0.f, 0.f};

        const float* fr = feat + (size_t)(rb + r) * 128 + g * 8;
        #pragma unroll
        for (int kq = 0; kq < 4; ++kq) {
            const float4 f0 = *(const float4*)(fr + kq * 32);
            const float4 f1 = *(const float4*)(fr + kq * 32 + 4);
            half8_t af;
            af[0] = (_Float16)f0.x; af[1] = (_Float16)f0.y;
            af[2] = (_Float16)f0.z; af[3] = (_Float16)f0.w;
            af[4] = (_Float16)f1.x; af[5] = (_Float16)f1.y;
            af[6] = (_Float16)f1.z; af[7] = (_Float16)f1.w;
            #pragma unroll
            for (int nt = 0; nt < 4; ++nt)
                acc[nt] = __builtin_amdgcn_mfma_f32_16x16x32_f16(
                    af, bfr[nt][kq], acc[nt], 0, 0, 0);
        }

        const int row0 = rb + g * 4;       // reg 0 rows are the anchors
        float ss = 0.0f, y[4];
        #pragma unroll
        for (int nt = 0; nt < 4; ++nt) {
            y[nt] = preluf(acc[nt][0] + bj[nt], a);
            ss = fmaf(y[nt], y[nt], ss);
        }
        ss += __shfl_xor(ss, 1, 16);
        ss += __shfl_xor(ss, 2, 16);
        ss += __shfl_xor(ss, 4, 16);
        ss += __shfl_xor(ss, 8, 16);
        const float inv = 1.0f / fmaxf(sqrtf(ss), EPSN);
        #pragma unroll
        for (int nt = 0; nt < 4; ++nt)
            out_anchor[(size_t)(row0 >> 2) * 64 + nt * 16 + r] = y[nt] * inv;
        #pragma unroll
        for (int nt = 0; nt < 4; ++nt)
            in_feat[(size_t)row0 * 64 + nt * 16 + r] = __float2half(0.0f);
        #pragma unroll
        for (int reg = 1; reg < 4; ++reg)
            #pragma unroll
            for (int nt = 0; nt < 4; ++nt)
                in_feat[(size_t)(row0 + reg) * 64 + nt * 16 + r] =
                    __float2half(acc[nt][reg]);
    }
}

// ---------------- fused K1 + S1: count blocks FIRST, transform fills -------
// R9 put count blocks last -> they ran as an idle tail (occ 21%, VALU 8%).
// Count-first makes both co-resident from t=0.
__global__ __launch_bounds__(256) void k_tc(
    const float* __restrict__ feat, const float* __restrict__ weight,
    const float* __restrict__ bias, const float* __restrict__ prelu_a,
    __half* __restrict__ in_feat, float* __restrict__ out_anchor, int N,
    int nwg, int twT,
    const int* __restrict__ esrc, const int* __restrict__ edst, int E,
    unsigned* __restrict__ C)
{
    __shared__ unsigned hist[NBC];
    const int t = threadIdx.x;
    if ((int)blockIdx.x >= nwg) {
        const int tIdx = (int)blockIdx.x - nwg;
        const int wid  = tIdx * 4 + (t >> 6);
        transform_body(feat, weight, bias, prelu_a, in_feat, out_anchor,
                       N, wid, twT);
        return;
    }
    const int blk = (int)blockIdx.x;
    hist[t] = 0;
    __syncthreads();
    const int base = blk * CHK;
    for (int r = 0; r < CHK / (16 * 256); ++r) {
        int d[16];
        #pragma unroll
        for (int i = 0; i < 16; ++i) {
            const int idx = base + (r * 16 + i) * 256 + t;
            d[i] = -1;
            if (idx < E) {
                const int s = esrc[idx];
                if ((s & 3) != 0) d[i] = edst[idx];   // drop zero-msg edges
            }
        }
        #pragma unroll
        for (int i = 0; i < 16; ++i)
            if (d[i] >= 0) atomicAdd(&hist[((unsigned)d[i]) >> 10], 1u);
    }
    __syncthreads();
    C[(size_t)blk * NBC + t] = hist[t];
}

// ---------------- S2: per-bucket exclusive scan over blocks, IN PLACE ------
__global__ __launch_bounds__(256) void s_scanA(
    unsigned* __restrict__ C, unsigned* __restrict__ T, int nwg)
{
    __shared__ unsigned ssum[256];
    const int i = blockIdx.x;
    const int t = threadIdx.x;
    const int PER = (nwg + 255) / 256;           // <= 4
    unsigned vals[4];
    unsigned run = 0;
    for (int p = 0; p < PER; ++p) {
        const int blk = t * PER + p;
        const unsigned v = (blk < nwg) ? C[(size_t)blk * NBC + i] : 0u;
        vals[p] = run;
        run += v;
    }
    ssum[t] = run;
    __syncthreads();
    for (int off = 1; off < 256; off <<= 1) {
        unsigned x = (t >= off) ? ssum[t - off] : 0u;
        __syncthreads();
        ssum[t] += x;
        __syncthreads();
    }
    const unsigned texcl = ssum[t] - run;
    for (int p = 0; p < PER; ++p) {
        const int blk = t * PER + p;
        if (blk < nwg) C[(size_t)blk * NBC + i] = texcl + vals[p];
    }
    if (t == 255) T[i] = ssum[255];
}

// ---------------- S3: block-local counting sort, 1024 threads --------------
// R9 accounting: scatter4+sortfine ~250us at 8/4 waves per CU -- pure
// latency exposure. 1024 threads: 2 blocks x 16 waves = 32 waves/CU.
// record: x = src(18) | wq(14), y = dst.
__global__ __launch_bounds__(1024) void s_scatter4(
    const int* __restrict__ esrc, const int* __restrict__ edst,
    const float* __restrict__ ew, int E,
    const unsigned* __restrict__ C, const unsigned* __restrict__ T, int nwg,
    uint2* __restrict__ recs)
{
    __shared__ uint2    buf[CHK];        // 64 KB
    __shared__ unsigned cur[NBC];
    __shared__ unsigned cb [NBC];
    __shared__ unsigned ssum[NBC];
    const int blk = blockIdx.x;
    const int t   = threadIdx.x;

    unsigned Tt = 0, own = 0, nxt = 0;
    if (t < NBC) {
        Tt  = T[t];
        own = C[(size_t)blk * NBC + t];
        nxt = (blk + 1 < nwg) ? C[(size_t)(blk + 1) * NBC + t] : Tt;
        ssum[t] = Tt;
    }
    __syncthreads();
    for (int off = 1; off < NBC; off <<= 1) {
        unsigned x = 0;
        if (t < NBC && t >= off) x = ssum[t - off];
        __syncthreads();
        if (t < NBC) ssum[t] += x;
        __syncthreads();
    }
    const unsigned basepl = (t < NBC) ? (ssum[t] - Tt) : 0u;
    __syncthreads();

    const unsigned myc = nxt - own;
    if (t < NBC) ssum[t] = myc;
    __syncthreads();
    for (int off = 1; off < NBC; off <<= 1) {
        unsigned x = 0;
        if (t < NBC && t >= off) x = ssum[t - off];
        __syncthreads();
        if (t < NBC) ssum[t] += x;
        __syncthreads();
    }
    if (t < NBC) {
        const unsigned excl = ssum[t] - myc;
        cur[t] = excl;
        cb[t]  = basepl + own - excl;    // unsigned wrap ok
    }
    __syncthreads();
    const unsigned cnt = ssum[NBC - 1];

    const int base = blk * CHK;
    int s8[8], d8[8]; float w8[8];
    #pragma unroll
    for (int i = 0; i < 8; ++i) {
        const int idx = base + i * 1024 + t;
        const bool ok = (idx < E);
        s8[i] = ok ? esrc[idx] : 0;
        d8[i] = ok ? edst[idx] : 0;
        w8[i] = ok ? ew[idx]   : 0.0f;
        if (!ok || (s8[i] & 3) == 0) d8[i] = -1;
    }
    #pragma unroll
    for (int i = 0; i < 8; ++i) {
        if (d8[i] >= 0) {
            const unsigned slot = atomicAdd(&cur[((unsigned)d8[i]) >> 10], 1u);
            const unsigned wq = min((unsigned)(w8[i] * WQS + 0.5f), 16383u);
            buf[slot] = make_uint2(((unsigned)s8[i]) | (wq << 18),
                                   (unsigned)d8[i]);
        }
    }
    __syncthreads();
    for (unsigned i = t; i < cnt; i += 1024) {     // coalesced flush
        const uint2 rr = buf[i];
        recs[cb[rr.y >> 10] + i] = rr;
    }
}

// ---------------- S4: per-bucket fine sort, 1024 threads -------------------
// hist/cur: exactly one row per thread. 16 waves/CU (was 4).
__global__ __launch_bounds__(1024) void s_sortfine(
    const uint2* __restrict__ recs, const unsigned* __restrict__ T,
    unsigned* __restrict__ recf, unsigned* __restrict__ rs, int N)
{
    __shared__ unsigned hist[RBF];       // row counts, then row cursors
    __shared__ unsigned sc[RBF];
    __shared__ unsigned bs[NBC];
    const int t = threadIdx.x;
    const int b = blockIdx.x;

    const unsigned Tb = T[b];
    if (t < NBC) bs[t] = T[t];
    __syncthreads();
    for (int off = 1; off < NBC; off <<= 1) {
        unsigned x = 0;
        if (t < NBC && t >= off) x = bs[t - off];
        __syncthreads();
        if (t < NBC) bs[t] += x;
        __syncthreads();
    }
    const unsigned end   = bs[b];
    const unsigned start = end - Tb;
    if (b == NBC - 1 && t == 0) rs[N] = bs[NBC - 1];
    __syncthreads();

    hist[t] = 0;
    __syncthreads();
    for (unsigned i = start + t; i < end; i += 1024)
        atomicAdd(&hist[recs[i].y & (RBF - 1u)], 1u);
    __syncthreads();
    const unsigned my = hist[t];
    sc[t] = my;
    __syncthreads();
    for (int off = 1; off < RBF; off <<= 1) {
        unsigned x = (t >= off) ? sc[t - off] : 0u;
        __syncthreads();
        sc[t] += x;
        __syncthreads();
    }
    const unsigned rowstart = start + sc[t] - my;
    hist[t] = rowstart;                  // reuse as cursor
    rs[b * RBF + t] = rowstart;
    __syncthreads();
    for (unsigned i = start + t; i < end; i += 1024) {
        const uint2 r = recs[i];
        const unsigned slot = atomicAdd(&hist[r.y & (RBF - 1u)], 1u);
        recf[slot] = r.x;
    }
}

// ---------------- S5: paired-edge gather, 2 cols/lane ----------------------
__global__ __launch_bounds__(256) void s_accum5(
    const __half* __restrict__ in_feat, const unsigned* __restrict__ recf,
    const unsigned* __restrict__ rs, float* __restrict__ h,
    int NROWS, int totalWaves)
{
    const char* ifb  = (const char*)in_feat;
    const int   lane = threadIdx.x & 63;
    const int   l32  = lane & 31;
    const int   hsel = lane >> 5;                 // 0: even edge, 1: odd edge
    const unsigned colb = (unsigned)l32 * 4u;     // byte offset of col pair
    const int wid = (int)((blockIdx.x * (size_t)blockDim.x + threadIdx.x) >> 6);

    for (int row = wid; row < NROWS; row += totalWaves) {
        const unsigned s = rs[row], e = rs[row + 1];
        float acc0 = 0.0f, acc1 = 0.0f;
        for (unsigned done = s; done < e; done += 64u) {
            const int c = (int)min(64u, e - done);
            unsigned rcd = 0u;
            if (lane < c) rcd = recf[done + lane];   // coalesced 4B x c
            const int pairs = (c + 1) >> 1;
            for (int p0 = 0; p0 < pairs; p0 += PU) {
                unsigned px[PU];
                __half2  hh[PU];
                float    wj[PU];
                #pragma unroll
                for (int pp = 0; pp < PU; ++pp) {
                    const int jv = (p0 + pp) * 2 + hsel;
                    px[pp] = (unsigned)__shfl((int)rcd, jv, 64);
                }
                #pragma unroll
                for (int pp = 0; pp < PU; ++pp) {
                    const unsigned voff =
                        ((px[pp] & 0x3FFFFu) << 7) + colb;
                    hh[pp] = *(const __half2*)(ifb + (size_t)voff);
                    wj[pp] = (float)(px[pp] >> 18);
                }
                #pragma unroll
                for (int pp = 0; pp < PU; ++pp) {
                    acc0 = fmaf(__half2float(__low2half(hh[pp])),  wj[pp], acc0);
                    acc1 = fmaf(__half2float(__high2half(hh[pp])), wj[pp], acc1);
                }
            }
        }
        acc0 += __shfl_xor(acc0, 32, 64);
        acc1 += __shfl_xor(acc1, 32, 64);
        if (hsel == 0) {
            float2 o;
            o.x = acc0 * (1.0f / WQS);
            o.y = acc1 * (1.0f / WQS);
            *(float2*)(h + ((size_t)row << 6) + 2 * l32) = o;
        }
    }
}

// ---------------- K1 fallback (VALU, row-per-lane) -------------------------
__global__ __launch_bounds__(256) void k_transform2(
    const float* __restrict__ feat, const float* __restrict__ weight,
    const float* __restrict__ bias, const float* __restrict__ prelu_a,
    __half* __restrict__ in_feat, float* __restrict__ out_anchor,
    int N, int totalWaves)
{
    const int lane  = threadIdx.x & 63;
    const int wid   = (int)((blockIdx.x * (size_t)blockDim.x + threadIdx.x) >> 6);
    const int tiles = (N + 63) >> 6;

    for (int tile = wid; tile < tiles; tile += totalWaves) {
        const int row = tile * 64 + lane;
        if (row >= N) continue;

        float acc[64];
        #pragma unroll
        for (int j = 0; j < 64; ++j) acc[j] = 0.0f;

        const float4* fp = (const float4*)(feat + (size_t)row * 128);
        #pragma unroll 4
        for (int kc = 0; kc < 32; ++kc) {
            const float4 f = fp[kc];
            const float fs[4] = {f.x, f.y, f.z, f.w};
            #pragma unroll
            for (int kk = 0; kk < 4; ++kk) {
                const float fv = fs[kk];
                const float* wr = weight + (kc * 4 + kk) * 64;
                #pragma unroll
                for (int j = 0; j < 64; ++j)
                    acc[j] = fmaf(fv, wr[j], acc[j]);
            }
        }

        if ((row & 3) == 0) {
            const float a = prelu_a[0];
            float ss = 0.0f;
            #pragma unroll
            for (int j = 0; j < 64; ++j) {
                acc[j] = preluf(acc[j] + bias[j], a);
                ss = fmaf(acc[j], acc[j], ss);
            }
            const float inv = 1.0f / fmaxf(sqrtf(ss), EPSN);
            float* ap = out_anchor + (size_t)(row >> 2) * 64;
            #pragma unroll
            for (int j = 0; j < 64; ++j) ap[j] = acc[j] * inv;
            #pragma unroll
            for (int j = 0; j < 64; ++j)
                in_feat[(size_t)row * 64 + j] = __float2half(0.0f);
        } else {
            #pragma unroll
            for (int j = 0; j < 64; ++j)
                in_feat[(size_t)row * 64 + j] = __float2half(acc[j]);
        }
    }
}

// ---------------- fallback K2 (atomic scatter) ----------------------------
#define K2_U 8
__global__ __launch_bounds__(256) void k_edges(
    const __half* __restrict__ in_feat, const int* __restrict__ esrc,
    const int* __restrict__ edst, const float* __restrict__ ew,
    float* __restrict__ h, int E, int totalWaves)
{
    const int lane = threadIdx.x & 63;
    int wid = (int)((blockIdx.x * (size_t)blockDim.x + threadIdx.x) >> 6);
    wid = __builtin_amdgcn_readfirstlane(wid);
    const int chunk = (E + totalWaves - 1) / totalWaves;
    int e0 = wid * chunk;
    int e1 = min(e0 + chunk, E);
    for (int base = e0; base < e1; base += K2_U) {
        const int nb = min(K2_U, e1 - base);
        int s[K2_U], d[K2_U]; float w[K2_U];
        #pragma unroll
        for (int j = 0; j < K2_U; ++j) {
            int idx = base + ((j < nb) ? j : 0);
            s[j] = esrc[idx]; d[j] = edst[idx]; w[j] = ew[idx];
        }
        float v[K2_U];
        #pragma unroll
        for (int j = 0; j < K2_U; ++j)
            v[j] = __half2float(in_feat[((size_t)s[j] << 6) + lane]);
        #pragma unroll
        for (int j = 0; j < K2_U; ++j)
            if (j < nb) atomicAdd(h + ((size_t)d[j] << 6) + lane, v[j] * w[j]);
    }
}

// ---------------- K3: activation + pool + two GEMVs + l2norm --------------
__global__ __launch_bounds__(256) void k_finalize(
    const float* __restrict__ h, const float* __restrict__ bias,
    const float* __restrict__ prelu_a,
    const float* __restrict__ w_sub, const float* __restrict__ b_sub,
    const float* __restrict__ w_gcn, const float* __restrict__ b_gcn,
    float* __restrict__ out_sub, float* __restrict__ out_gcn,
    int G, int totalWaves)
{
    const int lane = threadIdx.x & 63;
    const int wid = (int)((blockIdx.x * (size_t)blockDim.x + threadIdx.x) >> 6);

    float wsreg[64], wgreg[64];
    #pragma unroll
    for (int k = 0; k < 64; ++k) wsreg[k] = w_sub[lane * 64 + k];
    #pragma unroll
    for (int k = 0; k < 64; ++k) wgreg[k] = w_gcn[lane * 64 + k];
    const float bj  = bias[lane];
    const float bsj = b_sub[lane];
    const float bgj = b_gcn[lane];
    const float a   = prelu_a[0];

    for (int g = wid; g < G; g += totalWaves) {
        const float* hp = h + (size_t)g * 256;
        float p0 = preluf(hp[lane]       + bj, a);
        float p1 = preluf(hp[64  + lane] + bj, a);
        float p2 = preluf(hp[128 + lane] + bj, a);
        float p3 = preluf(hp[192 + lane] + bj, a);
        float pool = (p0 + p1 + p2 + p3) * 0.25f;
        float gcn  = p0;

        float as = bsj, ag = bgj;
        #pragma unroll
        for (int k = 0; k < 64; ++k) {
            as = fmaf(rdlane(pool, k), wsreg[k], as);
            ag = fmaf(rdlane(gcn,  k), wgreg[k], ag);
        }
        float ss = as * as, sg = ag * ag;
        #pragma unroll
        for (int off = 32; off >= 1; off >>= 1) {
            ss += __shfl_xor(ss, off, 64);
            sg += __shfl_xor(sg, off, 64);
        }
        out_sub[(size_t)g * 64 + lane] = as / fmaxf(sqrtf(ss), EPSN);
        out_gcn[(size_t)g * 64 + lane] = ag / fmaxf(sqrtf(sg), EPSN);
    }
}

extern "C" void kernel_launch(void* const* d_in, const int* in_sizes, int n_in,
                              void* d_out, int out_size, void* d_ws, size_t ws_size,
                              hipStream_t stream)
{
    const float* feat    = (const float*)d_in[0];
    const int*   esrc    = (const int*)  d_in[1];
    const int*   edst    = (const int*)  d_in[2];
    const float* ew      = (const float*)d_in[3];
    const float* weight  = (const float*)d_in[4];
    const float* bias    = (const float*)d_in[5];
    const float* prelu_a = (const float*)d_in[6];
    const float* w_sub   = (const float*)d_in[7];
    const float* b_sub   = (const float*)d_in[8];
    const float* w_gcn   = (const float*)d_in[9];
    const float* b_gcn   = (const float*)d_in[10];

    const int N = in_sizes[0] / 128;
    const int E = in_sizes[1];
    const int G = N / 4;
    const int nwg = (E + CHK - 1) / CHK;

    // ws layout (sorted path; bytes). AH = N*64*2 (fp16), A = N*64*4:
    //   in_feat : [0, AH)
    //   h       : [AH, AH+A)     -- written by s_accum5 (after sortfine)
    //   recs    : [AH, AH+E*8)   -- overlays h; dead before s_accum5 runs
    //   recf    : [AH+A, +E*4)
    //   C       : nwg*NBC*4         (scanned IN PLACE)
    //   T       : NBC*4
    //   rs      : (N+1)*4
    char* wsb = (char*)d_ws;
    const size_t AH    = (size_t)N * 64 * 2;
    const size_t A     = (size_t)N * 64 * 4;
    const size_t offRf = AH + A;
    const size_t offC  = offRf + (size_t)E * 4;
    const size_t offT  = offC  + (size_t)nwg * NBC * 4;
    const size_t offRs = offT  + (size_t)NBC * 4;
    const size_t ws_need = offRs + (size_t)(N + 1) * 4;

    __half*   in_feat = (__half*)wsb;
    float*    h       = (float*)(wsb + AH);
    uint2*    recs    = (uint2*)(wsb + AH);
    unsigned* recf    = (unsigned*)(wsb + offRf);
    unsigned* C       = (unsigned*)(wsb + offC);
    unsigned* T       = (unsigned*)(wsb + offT);
    unsigned* rs      = (unsigned*)(wsb + offRs);

    float* out        = (float*)d_out;
    float* out_sub    = out;
    float* out_anchor = out + (size_t)G * 64;
    float* out_gcn    = out + (size_t)2 * G * 64;

    const bool sorted_path =
        (N == NBC * RBF) && (nwg <= NWGMAX) && ((size_t)E * 8 <= A) &&
        (ws_size >= ws_need);

    if (sorted_path) {
        {   // fused: count blocks FIRST (nwg), then transform (2048 blocks)
            const int nbT = 2048, twT = nbT * 4;
            k_tc<<<nwg + nbT, 256, 0, stream>>>(feat, weight, bias, prelu_a,
                                                in_feat, out_anchor, N, nwg, twT,
                                                esrc, edst, E, C);
        }
        s_scanA   <<<NBC, 256, 0, stream>>>(C, T, nwg);
        s_scatter4<<<nwg, 1024, 0, stream>>>(esrc, edst, ew, E, C, T, nwg, recs);
        s_sortfine<<<NBC, 1024, 0, stream>>>(recs, T, recf, rs, N);
        {
            const int blocks = 2048, tw = blocks * 4;   // 8192 waves, 32 rows each
            s_accum5<<<blocks, 256, 0, stream>>>(in_feat, recf, rs, h, N, tw);
        }
        {
            const int blocks = 4096, tw = blocks * 4;
            k_finalize<<<blocks, 256, 0, stream>>>(h, bias, prelu_a, w_sub, b_sub,
                                                   w_gcn, b_gcn, out_sub, out_gcn, G, tw);
        }
    } else if (ws_size >= AH + A) {
        {
            const int blocks = 1024, tw = blocks * 4;
            k_transform2<<<blocks, 256, 0, stream>>>(feat, weight, bias, prelu_a,
                                                     in_feat, out_anchor, N, tw);
        }
        hipMemsetAsync(h, 0, A, stream);
        const int blocks = 2048, tw = blocks * 4;
        k_edges<<<blocks, 256, 0, stream>>>(in_feat, esrc, edst, ew, h, E, tw);
        const int fblocks = 4096, ftw = fblocks * 4;
        k_finalize<<<fblocks, 256, 0, stream>>>(h, bias, prelu_a, w_sub, b_sub,
                                                w_gcn, b_gcn, out_sub, out_gcn, G, ftw);
    }
}

// Round 13
// 445.057 us; speedup vs baseline: 1.4194x; 1.0382x over previous
//
#include <hip/hip_runtime.h>
#include <hip/hip_fp16.h>

#define EPSN 1e-12f
#define NBC  256             // coarse dst buckets (dst >> 10), 1024 rows each
#define RBF  1024            // rows per coarse bucket
#define CHK  8192            // edges per count/scatter workgroup (nwg = 512)
#define NWGMAX 1024
#define PU   4               // edge-PAIRS in flight per wave in accumulate
#define WQS  16384.0f        // weight quantization scale (14 bits)
#define TP   68              // staged-tile pitch in halfs

typedef _Float16 half8_t __attribute__((ext_vector_type(8)));
typedef float    f32x4  __attribute__((ext_vector_type(4)));
typedef unsigned uint_ma __attribute__((may_alias));   // TBAA bridge for LDS
                                                       // type-punned read-back

__device__ __forceinline__ float rdlane(float v, int k) {
    return __int_as_float(__builtin_amdgcn_readlane(__float_as_int(v), k));
}
__device__ __forceinline__ float preluf(float x, float a) {
    return x >= 0.0f ? x : a * x;
}

// ---------------- fused K1 + S1 ---------------------------------------------
// count blocks first; transform blocks:
//  - weight staged once/block into LDS transposed fp16 -> bfr via 16
//    ds_read_b128/wave (was 128 scalar VMEM gathers/wave).
//    R11/R12 BUG: staging loop covered only 512 of 2048 float4s (1/4 of
//    weight) -> wT rows k>=32 uninitialized -> NaN. Fixed: 8 float4/thread,
//    idx = i*256 + t (each load instruction coalesced).
//  - output staged via per-wave LDS tile -> 2 global_store_dwordx4/tile-lane,
//    with __syncthreads() + may_alias read-back (ordering hygiene).
__global__ __launch_bounds__(256) void k_tc(
    const float* __restrict__ feat, const float* __restrict__ weight,
    const float* __restrict__ bias, const float* __restrict__ prelu_a,
    __half* __restrict__ in_feat, float* __restrict__ out_anchor, int N,
    int nwg, int twT,
    const int* __restrict__ esrc, const int* __restrict__ edst, int E,
    unsigned* __restrict__ C)
{
    __shared__ unsigned  hist[NBC];
    __shared__ _Float16  wT[64 * 128];        // wT[c*128 + k] = weight[k][c]
    __shared__ _Float16  st[4][16 * TP];      // per-wave output staging

    const int t = threadIdx.x;

    if ((int)blockIdx.x < nwg) {              // ---- count branch ----
        const int blk = (int)blockIdx.x;
        hist[t] = 0;
        __syncthreads();
        const int base = blk * CHK;
        for (int r = 0; r < CHK / (16 * 256); ++r) {
            int d[16];
            #pragma unroll
            for (int i = 0; i < 16; ++i) {
                const int idx = base + (r * 16 + i) * 256 + t;
                d[i] = -1;
                if (idx < E) {
                    const int s = esrc[idx];
                    if ((s & 3) != 0) d[i] = edst[idx];
                }
            }
            #pragma unroll
            for (int i = 0; i < 16; ++i)
                if (d[i] >= 0) atomicAdd(&hist[((unsigned)d[i]) >> 10], 1u);
        }
        __syncthreads();
        C[(size_t)blk * NBC + t] = hist[t];
        return;
    }

    // ---- transform branch ----
    const int tIdx = (int)blockIdx.x - nwg;
    {   // stage weight -> LDS (transposed, fp16); 8 float4 loads/thread
        const float4* w4 = (const float4*)weight;    // 2048 float4 total
        #pragma unroll
        for (int i = 0; i < 8; ++i) {
            const int idx = i * 256 + t;             // 0..2047, coalesced
            const float4 f = w4[idx];
            const int k = (idx * 4) >> 6;
            const int c = (idx * 4) & 63;
            wT[(c + 0) * 128 + k] = (_Float16)f.x;
            wT[(c + 1) * 128 + k] = (_Float16)f.y;
            wT[(c + 2) * 128 + k] = (_Float16)f.z;
            wT[(c + 3) * 128 + k] = (_Float16)f.w;
        }
    }
    __syncthreads();

    const int wv   = t >> 6;
    const int lane = t & 63;
    const int r    = lane & 15;
    const int g    = lane >> 4;
    const int nt4  = N >> 4;

    half8_t bfr[4][4];                        // 16 x ds_read_b128
    #pragma unroll
    for (int nt = 0; nt < 4; ++nt)
        #pragma unroll
        for (int kq = 0; kq < 4; ++kq)
            bfr[nt][kq] =
                *(const half8_t*)&wT[(nt * 16 + r) * 128 + kq * 32 + g * 8];

    float bj[4];
    #pragma unroll
    for (int nt = 0; nt < 4; ++nt) bj[nt] = bias[nt * 16 + r];
    const float a = prelu_a[0];

    _Float16* stw = &st[wv][0];
    const int rrow = lane >> 2;               // read-back row (0..15)
    const int q    = lane & 3;                // read-back quarter

    // NOTE: all transform waves have identical trip counts (N = NBC*RBF),
    // so the in-loop __syncthreads is safe.
    for (int tt = tIdx * 4 + wv; tt < nt4; tt += twT) {
        const int rb = tt << 4;

        f32x4 acc[4];
        #pragma unroll
        for (int nt = 0; nt < 4; ++nt) acc[nt] = (f32x4){0.f, 0.f, 0.f, 0.f};

        const float* fr = feat + (size_t)(rb + r) * 128 + g * 8;
        #pragma unroll
        for (int kq = 0; kq < 4; ++kq) {
            const float4 f0 = *(const float4*)(fr + kq * 32);
            const float4 f1 = *(const float4*)(fr + kq * 32 + 4);
            half8_t af;
            af[0] = (_Float16)f0.x; af[1] = (_Float16)f0.y;
            af[2] = (_Float16)f0.z; af[3] = (_Float16)f0.w;
            af[4] = (_Float16)f1.x; af[5] = (_Float16)f1.y;
            af[6] = (_Float16)f1.z; af[7] = (_Float16)f1.w;
            #pragma unroll
            for (int nt = 0; nt < 4; ++nt)
                acc[nt] = __builtin_amdgcn_mfma_f32_16x16x32_f16(
                    af, bfr[nt][kq], acc[nt], 0, 0, 0);
        }

        // anchor rows: reg==0 (row0 = rb + g*4; rb%16==0 -> row%4 == reg)
        const int row0 = rb + g * 4;
        float ss = 0.0f, y[4];
        #pragma unroll
        for (int nt = 0; nt < 4; ++nt) {
            y[nt] = preluf(acc[nt][0] + bj[nt], a);
            ss = fmaf(y[nt], y[nt], ss);
        }
        ss += __shfl_xor(ss, 1, 16);
        ss += __shfl_xor(ss, 2, 16);
        ss += __shfl_xor(ss, 4, 16);
        ss += __shfl_xor(ss, 8, 16);
        const float inv = 1.0f / fmaxf(sqrtf(ss), EPSN);
        #pragma unroll
        for (int nt = 0; nt < 4; ++nt)
            out_anchor[(size_t)(row0 >> 2) * 64 + nt * 16 + r] = y[nt] * inv;

        // stage output tile in LDS
        const int lr0 = g * 4;
        #pragma unroll
        for (int nt = 0; nt < 4; ++nt)
            stw[lr0 * TP + nt * 16 + r] = (_Float16)0.0f;     // anchor row
        #pragma unroll
        for (int reg = 1; reg < 4; ++reg)
            #pragma unroll
            for (int nt = 0; nt < 4; ++nt)
                stw[(lr0 + reg) * TP + nt * 16 + r] = (_Float16)acc[nt][reg];

        __syncthreads();                      // fence: writes before reads

        // coalesced read-back (may_alias dword reads) + 32 B/lane store
        const uint_ma* rp32 = (const uint_ma*)&stw[rrow * TP + q * 16];
        unsigned v[8];
        #pragma unroll
        for (int i = 0; i < 8; ++i) v[i] = rp32[i];
        uint4* dst = (uint4*)(in_feat + (size_t)(rb + rrow) * 64 + q * 16);
        dst[0] = make_uint4(v[0], v[1], v[2], v[3]);
        dst[1] = make_uint4(v[4], v[5], v[6], v[7]);
    }
}

// ---------------- S2: per-bucket exclusive scan over blocks, IN PLACE ------
__global__ __launch_bounds__(256) void s_scanA(
    unsigned* __restrict__ C, unsigned* __restrict__ T, int nwg)
{
    __shared__ unsigned ssum[256];
    const int i = blockIdx.x;
    const int t = threadIdx.x;
    const int PER = (nwg + 255) / 256;
    unsigned vals[4];
    unsigned run = 0;
    for (int p = 0; p < PER; ++p) {
        const int blk = t * PER + p;
        const unsigned v = (blk < nwg) ? C[(size_t)blk * NBC + i] : 0u;
        vals[p] = run;
        run += v;
    }
    ssum[t] = run;
    __syncthreads();
    for (int off = 1; off < 256; off <<= 1) {
        unsigned x = (t >= off) ? ssum[t - off] : 0u;
        __syncthreads();
        ssum[t] += x;
        __syncthreads();
    }
    const unsigned texcl = ssum[t] - run;
    for (int p = 0; p < PER; ++p) {
        const int blk = t * PER + p;
        if (blk < nwg) C[(size_t)blk * NBC + i] = texcl + vals[p];
    }
    if (t == 255) T[i] = ssum[255];
}

// ---------------- S2b: bucket bases (computed ONCE, read by S3/S4) ---------
__global__ __launch_bounds__(256) void s_bases(
    const unsigned* __restrict__ T, unsigned* __restrict__ basep,
    unsigned* __restrict__ rs, int N)
{
    __shared__ unsigned sc[NBC];
    const int t = threadIdx.x;
    const unsigned my = T[t];
    sc[t] = my;
    __syncthreads();
    for (int off = 1; off < NBC; off <<= 1) {
        unsigned x = (t >= off) ? sc[t - off] : 0u;
        __syncthreads();
        sc[t] += x;
        __syncthreads();
    }
    basep[t] = sc[t] - my;
    if (t == NBC - 1) { basep[NBC] = sc[t]; rs[N] = sc[t]; }
}

// ---------------- S3: block-local counting sort (wave-scan prologue) -------
__global__ __launch_bounds__(1024) void s_scatter4(
    const int* __restrict__ esrc, const int* __restrict__ edst,
    const float* __restrict__ ew, int E,
    const unsigned* __restrict__ C, const unsigned* __restrict__ T,
    const unsigned* __restrict__ basep, int nwg,
    uint2* __restrict__ recs)
{
    __shared__ uint2    buf[CHK];        // 64 KB
    __shared__ unsigned cur[NBC];
    __shared__ unsigned cb [NBC];
    __shared__ unsigned cntS;
    const int blk = blockIdx.x;
    const int t   = threadIdx.x;

    if (t < 64) {                        // wave-0 shfl scan; 1 barrier total
        unsigned vals[4], ownv[4], run = 0;
        #pragma unroll
        for (int p = 0; p < 4; ++p) {
            const int b = t * 4 + p;
            const unsigned own = C[(size_t)blk * NBC + b];
            const unsigned nxt =
                (blk + 1 < nwg) ? C[(size_t)(blk + 1) * NBC + b] : T[b];
            ownv[p] = own;
            vals[p] = run;
            run += nxt - own;
        }
        unsigned inc = run;
        #pragma unroll
        for (int off = 1; off < 64; off <<= 1) {
            const unsigned x = __shfl_up(inc, off, 64);
            if (t >= off) inc += x;
        }
        const unsigned lexcl = inc - run;
        #pragma unroll
        for (int p = 0; p < 4; ++p) {
            const int b = t * 4 + p;
            const unsigned excl = lexcl + vals[p];
            cur[b] = excl;
            cb[b]  = basep[b] + ownv[p] - excl;   // unsigned wrap ok
        }
        if (t == 63) cntS = inc;
    }
    __syncthreads();
    const unsigned cnt = cntS;

    const int base = blk * CHK;
    int s8[8], d8[8]; float w8[8];
    #pragma unroll
    for (int i = 0; i < 8; ++i) {
        const int idx = base + i * 1024 + t;
        const bool ok = (idx < E);
        s8[i] = ok ? esrc[idx] : 0;
        d8[i] = ok ? edst[idx] : 0;
        w8[i] = ok ? ew[idx]   : 0.0f;
        if (!ok || (s8[i] & 3) == 0) d8[i] = -1;
    }
    #pragma unroll
    for (int i = 0; i < 8; ++i) {
        if (d8[i] >= 0) {
            const unsigned slot = atomicAdd(&cur[((unsigned)d8[i]) >> 10], 1u);
            const unsigned wq = min((unsigned)(w8[i] * WQS + 0.5f), 16383u);
            buf[slot] = make_uint2(((unsigned)s8[i]) | (wq << 18),
                                   (unsigned)d8[i]);
        }
    }
    __syncthreads();
    for (unsigned i = t; i < cnt; i += 1024) {     // coalesced flush
        const uint2 rr = buf[i];
        recs[cb[rr.y >> 10] + i] = rr;
    }
}

// ---------------- S4: per-bucket fine sort (hierarchical wave scan) --------
__global__ __launch_bounds__(1024) void s_sortfine(
    const uint2* __restrict__ recs, const unsigned* __restrict__ basep,
    unsigned* __restrict__ recf, unsigned* __restrict__ rs)
{
    __shared__ unsigned hist[RBF];       // counts, then cursors
    __shared__ unsigned wsum[16];
    const int t    = threadIdx.x;
    const int b    = blockIdx.x;
    const int lane = t & 63;
    const int wv   = t >> 6;

    const unsigned start = basep[b], end = basep[b + 1];

    hist[t] = 0;
    __syncthreads();
    for (unsigned i = start + t; i < end; i += 1024)
        atomicAdd(&hist[recs[i].y & (RBF - 1u)], 1u);
    __syncthreads();

    const unsigned my = hist[t];
    unsigned inc = my;
    #pragma unroll
    for (int off = 1; off < 64; off <<= 1) {
        const unsigned x = __shfl_up(inc, off, 64);
        if (lane >= off) inc += x;
    }
    if (lane == 63) wsum[wv] = inc;
    __syncthreads();
    if (t == 0) {
        unsigned r = 0;
        #pragma unroll
        for (int i = 0; i < 16; ++i) { const unsigned v = wsum[i]; wsum[i] = r; r += v; }
    }
    __syncthreads();
    const unsigned rowstart = start + wsum[wv] + inc - my;
    __syncthreads();                      // all reads of hist done
    hist[t] = rowstart;                   // reuse as cursor
    rs[b * RBF + t] = rowstart;
    __syncthreads();
    for (unsigned i = start + t; i < end; i += 1024) {
        const uint2 r = recs[i];
        const unsigned slot = atomicAdd(&hist[r.y & (RBF - 1u)], 1u);
        recf[slot] = r.x;
    }
}

// ---------------- S5: paired-edge gather, 2 cols/lane ----------------------
__global__ __launch_bounds__(256) void s_accum5(
    const __half* __restrict__ in_feat, const unsigned* __restrict__ recf,
    const unsigned* __restrict__ rs, float* __restrict__ h,
    int NROWS, int totalWaves)
{
    const char* ifb  = (const char*)in_feat;
    const int   lane = threadIdx.x & 63;
    const int   l32  = lane & 31;
    const int   hsel = lane >> 5;
    const unsigned colb = (unsigned)l32 * 4u;
    const int wid = (int)((blockIdx.x * (size_t)blockDim.x + threadIdx.x) >> 6);

    for (int row = wid; row < NROWS; row += totalWaves) {
        const unsigned s = rs[row], e = rs[row + 1];
        float acc0 = 0.0f, acc1 = 0.0f;
        for (unsigned done = s; done < e; done += 64u) {
            const int c = (int)min(64u, e - done);
            unsigned rcd = 0u;
            if (lane < c) rcd = recf[done + lane];
            const int pairs = (c + 1) >> 1;
            for (int p0 = 0; p0 < pairs; p0 += PU) {
                unsigned px[PU];
                __half2  hh[PU];
                float    wj[PU];
                #pragma unroll
                for (int pp = 0; pp < PU; ++pp) {
                    const int jv = (p0 + pp) * 2 + hsel;
                    px[pp] = (unsigned)__shfl((int)rcd, jv, 64);
                }
                #pragma unroll
                for (int pp = 0; pp < PU; ++pp) {
                    const unsigned voff = ((px[pp] & 0x3FFFFu) << 7) + colb;
                    hh[pp] = *(const __half2*)(ifb + (size_t)voff);
                    wj[pp] = (float)(px[pp] >> 18);
                }
                #pragma unroll
                for (int pp = 0; pp < PU; ++pp) {
                    acc0 = fmaf(__half2float(__low2half(hh[pp])),  wj[pp], acc0);
                    acc1 = fmaf(__half2float(__high2half(hh[pp])), wj[pp], acc1);
                }
            }
        }
        acc0 += __shfl_xor(acc0, 32, 64);
        acc1 += __shfl_xor(acc1, 32, 64);
        if (hsel == 0) {
            float2 o;
            o.x = acc0 * (1.0f / WQS);
            o.y = acc1 * (1.0f / WQS);
            *(float2*)(h + ((size_t)row << 6) + 2 * l32) = o;
        }
    }
}

// ---------------- K1 fallback (VALU, row-per-lane) -------------------------
__global__ __launch_bounds__(256) void k_transform2(
    const float* __restrict__ feat, const float* __restrict__ weight,
    const float* __restrict__ bias, const float* __restrict__ prelu_a,
    __half* __restrict__ in_feat, float* __restrict__ out_anchor,
    int N, int totalWaves)
{
    const int lane  = threadIdx.x & 63;
    const int wid   = (int)((blockIdx.x * (size_t)blockDim.x + threadIdx.x) >> 6);
    const int tiles = (N + 63) >> 6;

    for (int tile = wid; tile < tiles; tile += totalWaves) {
        const int row = tile * 64 + lane;
        if (row >= N) continue;

        float acc[64];
        #pragma unroll
        for (int j = 0; j < 64; ++j) acc[j] = 0.0f;

        const float4* fp = (const float4*)(feat + (size_t)row * 128);
        #pragma unroll 4
        for (int kc = 0; kc < 32; ++kc) {
            const float4 f = fp[kc];
            const float fs[4] = {f.x, f.y, f.z, f.w};
            #pragma unroll
            for (int kk = 0; kk < 4; ++kk) {
                const float fv = fs[kk];
                const float* wr = weight + (kc * 4 + kk) * 64;
                #pragma unroll
                for (int j = 0; j < 64; ++j)
                    acc[j] = fmaf(fv, wr[j], acc[j]);
            }
        }

        if ((row & 3) == 0) {
            const float a = prelu_a[0];
            float ss = 0.0f;
            #pragma unroll
            for (int j = 0; j < 64; ++j) {
                acc[j] = preluf(acc[j] + bias[j], a);
                ss = fmaf(acc[j], acc[j], ss);
            }
            const float inv = 1.0f / fmaxf(sqrtf(ss), EPSN);
            float* ap = out_anchor + (size_t)(row >> 2) * 64;
            #pragma unroll
            for (int j = 0; j < 64; ++j) ap[j] = acc[j] * inv;
            #pragma unroll
            for (int j = 0; j < 64; ++j)
                in_feat[(size_t)row * 64 + j] = __float2half(0.0f);
        } else {
            #pragma unroll
            for (int j = 0; j < 64; ++j)
                in_feat[(size_t)row * 64 + j] = __float2half(acc[j]);
        }
    }
}

// ---------------- fallback K2 (atomic scatter) ----------------------------
#define K2_U 8
__global__ __launch_bounds__(256) void k_edges(
    const __half* __restrict__ in_feat, const int* __restrict__ esrc,
    const int* __restrict__ edst, const float* __restrict__ ew,
    float* __restrict__ h, int E, int totalWaves)
{
    const int lane = threadIdx.x & 63;
    int wid = (int)((blockIdx.x * (size_t)blockDim.x + threadIdx.x) >> 6);
    wid = __builtin_amdgcn_readfirstlane(wid);
    const int chunk = (E + totalWaves - 1) / totalWaves;
    int e0 = wid * chunk;
    int e1 = min(e0 + chunk, E);
    for (int base = e0; base < e1; base += K2_U) {
        const int nb = min(K2_U, e1 - base);
        int s[K2_U], d[K2_U]; float w[K2_U];
        #pragma unroll
        for (int j = 0; j < K2_U; ++j) {
            int idx = base + ((j < nb) ? j : 0);
            s[j] = esrc[idx]; d[j] = edst[idx]; w[j] = ew[idx];
        }
        float v[K2_U];
        #pragma unroll
        for (int j = 0; j < K2_U; ++j)
            v[j] = __half2float(in_feat[((size_t)s[j] << 6) + lane]);
        #pragma unroll
        for (int j = 0; j < K2_U; ++j)
            if (j < nb) atomicAdd(h + ((size_t)d[j] << 6) + lane, v[j] * w[j]);
    }
}

// ---------------- K3: activation + pool + two GEMVs + l2norm --------------
__global__ __launch_bounds__(256) void k_finalize(
    const float* __restrict__ h, const float* __restrict__ bias,
    const float* __restrict__ prelu_a,
    const float* __restrict__ w_sub, const float* __restrict__ b_sub,
    const float* __restrict__ w_gcn, const float* __restrict__ b_gcn,
    float* __restrict__ out_sub, float* __restrict__ out_gcn,
    int G, int totalWaves)
{
    const int lane = threadIdx.x & 63;
    const int wid = (int)((blockIdx.x * (size_t)blockDim.x + threadIdx.x) >> 6);

    float wsreg[64], wgreg[64];
    #pragma unroll
    for (int k = 0; k < 64; ++k) wsreg[k] = w_sub[lane * 64 + k];
    #pragma unroll
    for (int k = 0; k < 64; ++k) wgreg[k] = w_gcn[lane * 64 + k];
    const float bj  = bias[lane];
    const float bsj = b_sub[lane];
    const float bgj = b_gcn[lane];
    const float a   = prelu_a[0];

    for (int g = wid; g < G; g += totalWaves) {
        const float* hp = h + (size_t)g * 256;
        float p0 = preluf(hp[lane]       + bj, a);
        float p1 = preluf(hp[64  + lane] + bj, a);
        float p2 = preluf(hp[128 + lane] + bj, a);
        float p3 = preluf(hp[192 + lane] + bj, a);
        float pool = (p0 + p1 + p2 + p3) * 0.25f;
        float gcn  = p0;

        float as = bsj, ag = bgj;
        #pragma unroll
        for (int k = 0; k < 64; ++k) {
            as = fmaf(rdlane(pool, k), wsreg[k], as);
            ag = fmaf(rdlane(gcn,  k), wgreg[k], ag);
        }
        float ss = as * as, sg = ag * ag;
        #pragma unroll
        for (int off = 32; off >= 1; off >>= 1) {
            ss += __shfl_xor(ss, off, 64);
            sg += __shfl_xor(sg, off, 64);
        }
        out_sub[(size_t)g * 64 + lane] = as / fmaxf(sqrtf(ss), EPSN);
        out_gcn[(size_t)g * 64 + lane] = ag / fmaxf(sqrtf(sg), EPSN);
    }
}

extern "C" void kernel_launch(void* const* d_in, const int* in_sizes, int n_in,
                              void* d_out, int out_size, void* d_ws, size_t ws_size,
                              hipStream_t stream)
{
    const float* feat    = (const float*)d_in[0];
    const int*   esrc    = (const int*)  d_in[1];
    const int*   edst    = (const int*)  d_in[2];
    const float* ew      = (const float*)d_in[3];
    const float* weight  = (const float*)d_in[4];
    const float* bias    = (const float*)d_in[5];
    const float* prelu_a = (const float*)d_in[6];
    const float* w_sub   = (const float*)d_in[7];
    const float* b_sub   = (const float*)d_in[8];
    const float* w_gcn   = (const float*)d_in[9];
    const float* b_gcn   = (const float*)d_in[10];

    const int N = in_sizes[0] / 128;
    const int E = in_sizes[1];
    const int G = N / 4;
    const int nwg = (E + CHK - 1) / CHK;

    // ws layout (sorted path; bytes). AH = N*64*2 (fp16), A = N*64*4:
    //   in_feat : [0, AH)
    //   h       : [AH, AH+A)     -- written by s_accum5 (after sortfine)
    //   recs    : [AH, AH+E*8)   -- overlays h; dead before s_accum5 runs
    //   recf    : [AH+A, +E*4)
    //   C       : nwg*NBC*4         (scanned IN PLACE)
    //   T       : NBC*4
    //   basep   : (NBC+1)*4
    //   rs      : (N+1)*4
    char* wsb = (char*)d_ws;
    const size_t AH    = (size_t)N * 64 * 2;
    const size_t A     = (size_t)N * 64 * 4;
    const size_t offRf = AH + A;
    const size_t offC  = offRf + (size_t)E * 4;
    const size_t offT  = offC  + (size_t)nwg * NBC * 4;
    const size_t offBp = offT  + (size_t)NBC * 4;
    const size_t offRs = offBp + (size_t)(NBC + 1) * 4;
    const size_t ws_need = offRs + (size_t)(N + 1) * 4;

    __half*   in_feat = (__half*)wsb;
    float*    h       = (float*)(wsb + AH);
    uint2*    recs    = (uint2*)(wsb + AH);
    unsigned* recf    = (unsigned*)(wsb + offRf);
    unsigned* C       = (unsigned*)(wsb + offC);
    unsigned* T       = (unsigned*)(wsb + offT);
    unsigned* basep   = (unsigned*)(wsb + offBp);
    unsigned* rs      = (unsigned*)(wsb + offRs);

    float* out        = (float*)d_out;
    float* out_sub    = out;
    float* out_anchor = out + (size_t)G * 64;
    float* out_gcn    = out + (size_t)2 * G * 64;

    const bool sorted_path =
        (N == NBC * RBF) && (nwg <= NWGMAX) && ((size_t)E * 8 <= A) &&
        (ws_size >= ws_need);

    if (sorted_path) {
        {   // fused: count blocks first (nwg), then transform (2048 blocks)
            const int nbT = 2048, twT = nbT * 4;
            k_tc<<<nwg + nbT, 256, 0, stream>>>(feat, weight, bias, prelu_a,
                                                in_feat, out_anchor, N, nwg, twT,
                                                esrc, edst, E, C);
        }
        s_scanA   <<<NBC, 256, 0, stream>>>(C, T, nwg);
        s_bases   <<<1, 256, 0, stream>>>(T, basep, rs, N);
        s_scatter4<<<nwg, 1024, 0, stream>>>(esrc, edst, ew, E, C, T, basep,
                                             nwg, recs);
        s_sortfine<<<NBC, 1024, 0, stream>>>(recs, basep, recf, rs);
        {
            const int blocks = 2048, tw = blocks * 4;
            s_accum5<<<blocks, 256, 0, stream>>>(in_feat, recf, rs, h, N, tw);
        }
        {
            const int blocks = 4096, tw = blocks * 4;
            k_finalize<<<blocks, 256, 0, stream>>>(h, bias, prelu_a, w_sub, b_sub,
                                                   w_gcn, b_gcn, out_sub, out_gcn, G, tw);
        }
    } else if (ws_size >= AH + A) {
        {
            const int blocks = 1024, tw = blocks * 4;
            k_transform2<<<blocks, 256, 0, stream>>>(feat, weight, bias, prelu_a,
                                                     in_feat, out_anchor, N, tw);
        }
        hipMemsetAsync(h, 0, A, stream);
        const int blocks = 2048, tw = blocks * 4;
        k_edges<<<blocks, 256, 0, stream>>>(in_feat, esrc, edst, ew, h, E, tw);
        const int fblocks = 4096, ftw = fblocks * 4;
        k_finalize<<<fblocks, 256, 0, stream>>>(h, bias, prelu_a, w_sub, b_sub,
                                                w_gcn, b_gcn, out_sub, out_gcn, G, ftw);
    }
}